// Round 6
// baseline (440.227 us; speedup 1.0000x reference)
//
#include <hip/hip_runtime.h>
#include <stdint.h>

#define NUM_C 16
#define NUM_B 8
#define RANGES 64                        // hash sub-ranges per class
#define NBKT (NUM_C * RANGES)            // 1024 buckets per batch
#define CHUNK 4096                       // items per scatter chunk
#define TAB_SLOTS 4096                   // LDS hash slots (load ~0.48)
#define MAX_NB 4                         // batches per round (L2 write-set cap)

__device__ __forceinline__ unsigned hash_u32(unsigned h) {
    h ^= h >> 16; h *= 0x85ebca6bu;
    h ^= h >> 13; h *= 0xc2b2ae35u;
    h ^= h >> 16;
    return h;
}
__device__ __forceinline__ unsigned canon_key(float v) {
    unsigned k = __float_as_uint(v);
    return (k == 0x80000000u) ? 0u : k;          // -0.0 == +0.0
}
__device__ __forceinline__ unsigned bucket_of(unsigned key, int c) {
    return ((unsigned)c << 6) | (hash_u32(key) >> 26);
}

// K1: per-chunk bucket histogram -> counts[lb][seg][bkt] (coalesced write).
__global__ void __launch_bounds__(256)
hist_kernel(const float* __restrict__ x, const int* __restrict__ t,
            long long N, int bbase, int nblk,
            unsigned* __restrict__ counts)
{
    __shared__ unsigned hist[NBKT];
    const int lb  = blockIdx.x / nblk;
    const int blk = blockIdx.x % nblk;
    const int b   = bbase + lb;
    const long long base = (long long)blk * CHUNK;
    const int count = (int)((N - base < CHUNK) ? (N - base) : CHUNK);
    const float* xb = x + (size_t)b * N + base;
    const int*   tb = t + (size_t)b * N + base;

    for (int i = threadIdx.x; i < NBKT; i += 256) hist[i] = 0u;
    __syncthreads();

    const bool vec_ok = ((N & 3) == 0);
    const int n4 = vec_ok ? (count >> 2) : 0;
    for (int i = threadIdx.x; i < n4; i += 256) {
        float4 v  = ((const float4*)xb)[i];
        int4   cc = ((const int4*)tb)[i];
        atomicAdd(&hist[bucket_of(canon_key(v.x), cc.x)], 1u);
        atomicAdd(&hist[bucket_of(canon_key(v.y), cc.y)], 1u);
        atomicAdd(&hist[bucket_of(canon_key(v.z), cc.z)], 1u);
        atomicAdd(&hist[bucket_of(canon_key(v.w), cc.w)], 1u);
    }
    for (int i = (n4 << 2) + threadIdx.x; i < count; i += 256)
        atomicAdd(&hist[bucket_of(canon_key(xb[i]), tb[i])], 1u);
    __syncthreads();

    unsigned* og = counts + ((size_t)lb * nblk + blk) * NBKT;
    for (int i = threadIdx.x; i < NBKT; i += 256) og[i] = hist[i];
}

// K2: transpose counts [seg][bkt] -> countsT [bkt][seg].
__global__ void __launch_bounds__(256)
transpose_kernel(const unsigned* __restrict__ src_, unsigned* __restrict__ dst_,
                 int nblk)
{
    __shared__ unsigned tile[32][33];
    const int lb   = blockIdx.z;
    const int seg0 = blockIdx.x * 32;
    const int bkt0 = blockIdx.y * 32;
    const unsigned* src = src_ + (size_t)lb * nblk * NBKT;
    unsigned*       dst = dst_ + (size_t)lb * nblk * NBKT;
    const int tx = threadIdx.x & 31, ty = threadIdx.x >> 5;
    #pragma unroll
    for (int j = 0; j < 32; j += 8) {
        int seg = seg0 + ty + j;
        if (seg < nblk) tile[ty + j][tx] = src[(size_t)seg * NBKT + bkt0 + tx];
    }
    __syncthreads();
    #pragma unroll
    for (int j = 0; j < 32; j += 8) {
        if (seg0 + tx < nblk)
            dst[(size_t)(bkt0 + ty + j) * nblk + seg0 + tx] = tile[tx][ty + j];
    }
}

// K3: per-bucket exclusive scan across chunks (in place on countsT row),
// bucket total -> totals[lb][bkt].  Requires nblk <= 512.
__global__ void __launch_bounds__(256)
rowscan_kernel(unsigned* __restrict__ countsT, unsigned* __restrict__ totals,
               int nblk)
{
    __shared__ unsigned a[512];
    unsigned* row = countsT + (size_t)blockIdx.x * nblk;
    const int tid = threadIdx.x;
    a[tid]       = (tid < nblk)       ? row[tid]       : 0u;
    a[tid + 256] = (tid + 256 < nblk) ? row[tid + 256] : 0u;
    __syncthreads();
    for (int st = 1; st < 512; st <<= 1) {
        unsigned v0 = a[tid]       + ((tid >= st)       ? a[tid - st]       : 0u);
        unsigned v1 = a[tid + 256] + ((tid + 256 >= st) ? a[tid + 256 - st] : 0u);
        __syncthreads();
        a[tid] = v0; a[tid + 256] = v1;
        __syncthreads();
    }
    if (tid < nblk)       row[tid]       = tid ? a[tid - 1] : 0u;
    if (tid + 256 < nblk) row[tid + 256] = a[tid + 255];
    if (tid == 0) totals[blockIdx.x] = a[511];
}

// K4: per-batch exclusive scan of 1024 bucket totals -> base[lb][0..1024]
// (sentinel base[1024] = N).
__global__ void __launch_bounds__(256)
basescan_kernel(const unsigned* __restrict__ totals, unsigned* __restrict__ base)
{
    __shared__ unsigned a[NBKT];
    const int lb = blockIdx.x, tid = threadIdx.x;
    const unsigned* tr = totals + (size_t)lb * NBKT;
    unsigned* br = base + (size_t)lb * (NBKT + 1);
    #pragma unroll
    for (int r = 0; r < 4; ++r) a[tid + r * 256] = tr[tid + r * 256];
    __syncthreads();
    for (int st = 1; st < NBKT; st <<= 1) {
        unsigned v[4];
        #pragma unroll
        for (int r = 0; r < 4; ++r) {
            int k = tid + r * 256;
            v[r] = a[k] + ((k >= st) ? a[k - st] : 0u);
        }
        __syncthreads();
        #pragma unroll
        for (int r = 0; r < 4; ++r) a[tid + r * 256] = v[r];
        __syncthreads();
    }
    #pragma unroll
    for (int r = 0; r < 4; ++r) {
        int k = tid + r * 256;
        br[k] = k ? a[k - 1] : 0u;
    }
    if (tid == 0) br[NBKT] = a[NBKT - 1];
}

// K5: transpose scanned countsT [bkt][seg] back to goff [seg][bkt], + base.
__global__ void __launch_bounds__(256)
addt_kernel(const unsigned* __restrict__ scanned, const unsigned* __restrict__ base,
            unsigned* __restrict__ goff, int nblk)
{
    __shared__ unsigned tile[32][33];
    const int lb   = blockIdx.z;
    const int seg0 = blockIdx.x * 32;
    const int bkt0 = blockIdx.y * 32;
    const unsigned* src = scanned + (size_t)lb * nblk * NBKT;
    const unsigned* br  = base + (size_t)lb * (NBKT + 1);
    unsigned*       dst = goff + (size_t)lb * nblk * NBKT;
    const int tx = threadIdx.x & 31, ty = threadIdx.x >> 5;
    #pragma unroll
    for (int j = 0; j < 32; j += 8) {
        if (seg0 + tx < nblk)
            tile[ty + j][tx] = src[(size_t)(bkt0 + ty + j) * nblk + seg0 + tx];
    }
    __syncthreads();
    #pragma unroll
    for (int j = 0; j < 32; j += 8) {
        int seg = seg0 + ty + j;
        if (seg < nblk)
            dst[(size_t)seg * NBKT + bkt0 + tx] = tile[tx][ty + j] + br[bkt0 + tx];
    }
}

// K6: placement scatter. Cursors seeded from counts row (no re-histogram);
// LDS counting sort of the chunk, then write each item to its exact
// globally-bucket-sorted position (runs -> consecutive addresses).
__global__ void __launch_bounds__(256)
scatter_kernel(const float* __restrict__ x, const int* __restrict__ t,
               long long N, int bbase, int nblk,
               const unsigned* __restrict__ counts,
               const unsigned* __restrict__ goff,
               unsigned* __restrict__ keysout)
{
    __shared__ unsigned hist[NBKT];              // counts -> cursors -> delta
    __shared__ unsigned sstart[NBKT];            // local run starts
    __shared__ unsigned lout[CHUNK];             // 16 KiB
    __shared__ unsigned short lbkt[CHUNK];       // 8 KiB
    __shared__ unsigned sscan[256];

    const int lb  = blockIdx.x / nblk;
    const int blk = blockIdx.x % nblk;
    const int b   = bbase + lb;
    const long long base = (long long)blk * CHUNK;
    const int count = (int)((N - base < CHUNK) ? (N - base) : CHUNK);
    const float* xb = x + (size_t)b * N + base;
    const int*   tb = t + (size_t)b * N + base;
    const unsigned* crow = counts + ((size_t)lb * nblk + blk) * NBKT;
    const unsigned* grow = goff   + ((size_t)lb * nblk + blk) * NBKT;

    for (int i = threadIdx.x; i < NBKT; i += 256) hist[i] = crow[i];
    __syncthreads();

    // exclusive scan over 1024 bins (4/thread) -> local cursors
    unsigned h0 = hist[threadIdx.x * 4 + 0];
    unsigned h1 = hist[threadIdx.x * 4 + 1];
    unsigned h2 = hist[threadIdx.x * 4 + 2];
    unsigned h3 = hist[threadIdx.x * 4 + 3];
    unsigned local = h0 + h1 + h2 + h3;
    sscan[threadIdx.x] = local;
    __syncthreads();
    for (int st = 1; st < 256; st <<= 1) {
        unsigned v = (threadIdx.x >= (unsigned)st) ? sscan[threadIdx.x - st] : 0u;
        __syncthreads();
        sscan[threadIdx.x] += v;
        __syncthreads();
    }
    unsigned excl = sscan[threadIdx.x] - local;
    unsigned o0 = excl, o1 = o0 + h0, o2 = o1 + h1, o3 = o2 + h2;
    hist[threadIdx.x * 4 + 0] = o0; sstart[threadIdx.x * 4 + 0] = o0;
    hist[threadIdx.x * 4 + 1] = o1; sstart[threadIdx.x * 4 + 1] = o1;
    hist[threadIdx.x * 4 + 2] = o2; sstart[threadIdx.x * 4 + 2] = o2;
    hist[threadIdx.x * 4 + 3] = o3; sstart[threadIdx.x * 4 + 3] = o3;
    __syncthreads();

    // scatter into LDS, recording bucket per slot
    const bool vec_ok = ((N & 3) == 0);
    const int n4 = vec_ok ? (count >> 2) : 0;
    for (int i = threadIdx.x; i < n4; i += 256) {
        float4 v  = ((const float4*)xb)[i];
        int4   cc = ((const int4*)tb)[i];
        unsigned k, bk, p;
        k = canon_key(v.x); bk = bucket_of(k, cc.x);
        p = atomicAdd(&hist[bk], 1u); lout[p] = k; lbkt[p] = (unsigned short)bk;
        k = canon_key(v.y); bk = bucket_of(k, cc.y);
        p = atomicAdd(&hist[bk], 1u); lout[p] = k; lbkt[p] = (unsigned short)bk;
        k = canon_key(v.z); bk = bucket_of(k, cc.z);
        p = atomicAdd(&hist[bk], 1u); lout[p] = k; lbkt[p] = (unsigned short)bk;
        k = canon_key(v.w); bk = bucket_of(k, cc.w);
        p = atomicAdd(&hist[bk], 1u); lout[p] = k; lbkt[p] = (unsigned short)bk;
    }
    for (int i = (n4 << 2) + threadIdx.x; i < count; i += 256) {
        unsigned k = canon_key(xb[i]);
        unsigned bk = bucket_of(k, tb[i]);
        unsigned p = atomicAdd(&hist[bk], 1u);
        lout[p] = k; lbkt[p] = (unsigned short)bk;
    }
    __syncthreads();

    // hist <- delta = global run start - local run start
    for (int i = threadIdx.x; i < NBKT; i += 256) hist[i] = grow[i] - sstart[i];
    __syncthreads();

    unsigned* kb = keysout + (size_t)lb * N;
    for (int i = threadIdx.x; i < count; i += 256)
        kb[hist[lbkt[i]] + i] = lout[i];
}

// K7: one block per (batch,bucket); bucket is one contiguous run. Packed
// (count<<32 | key) LDS table; best = max(count<<32 | (2^32-1 - ord(value)))
// -- max count, ties -> smallest value (reference tie-break).
__global__ void __launch_bounds__(256)
mode_kernel(const unsigned* __restrict__ keysout,
            const unsigned* __restrict__ base, long long N, int bbase,
            unsigned long long* __restrict__ best,   // [NUM_B*NUM_C], zeroed
            double* __restrict__ psum,               // [NUM_B*NBKT]
            unsigned* __restrict__ pcnt)             // [NUM_B*NBKT]
{
    __shared__ unsigned long long tab[TAB_SLOTS];    // 32 KiB
    __shared__ unsigned long long redb[4];
    __shared__ double reds[4];

    const unsigned lb  = blockIdx.x / NBKT;
    const unsigned bkt = blockIdx.x % NBKT;
    const unsigned c   = bkt >> 6;
    const unsigned b   = (unsigned)bbase + lb;

    for (int i = threadIdx.x; i < TAB_SLOTS; i += 256) tab[i] = 0ull;
    __syncthreads();

    const unsigned* br = base + (size_t)lb * (NBKT + 1);
    const unsigned s = br[bkt], e = br[bkt + 1];
    const unsigned* kb = keysout + (size_t)lb * N;

    double ls = 0.0;
    for (unsigned i = s + threadIdx.x; i < e; i += 256) {
        unsigned key = kb[i];
        ls += (double)__uint_as_float(key);
        unsigned h = hash_u32(key) & (TAB_SLOTS - 1);
        unsigned long long pk = (1ull << 32) | (unsigned long long)key;
        for (int p = 0; p < TAB_SLOTS; ++p) {        // bounded probe
            unsigned long long curv = tab[h];
            if (curv != 0ull && (unsigned)curv == key) {
                atomicAdd(&tab[h], 1ull << 32); break;
            }
            if (curv == 0ull) {
                unsigned long long old = atomicCAS(&tab[h], 0ull, pk);
                if (old == 0ull) break;
                if ((unsigned)old == key) { atomicAdd(&tab[h], 1ull << 32); break; }
            }
            h = (h + 1u) & (TAB_SLOTS - 1);
        }
    }
    __syncthreads();

    unsigned long long lbst = 0ull;
    for (int s2 = threadIdx.x; s2 < TAB_SLOTS; s2 += 256) {
        unsigned long long curv = tab[s2];
        if (curv) {
            unsigned k   = (unsigned)curv;
            unsigned ct  = (unsigned)(curv >> 32);
            unsigned ord = (k & 0x80000000u) ? ~k : (k | 0x80000000u);
            unsigned long long p = ((unsigned long long)ct << 32)
                                 | (unsigned long long)(0xFFFFFFFFu - ord);
            if (p > lbst) lbst = p;
        }
    }
    #pragma unroll
    for (int sh = 32; sh > 0; sh >>= 1) {
        unsigned long long ob = __shfl_down(lbst, sh);
        if (ob > lbst) lbst = ob;
        ls += __shfl_down(ls, sh);
    }
    const int wid = threadIdx.x >> 6;
    if ((threadIdx.x & 63) == 0) { redb[wid] = lbst; reds[wid] = ls; }
    __syncthreads();
    if (threadIdx.x == 0) {
        unsigned long long bb = 0ull; double ss = 0.0;
        #pragma unroll
        for (int i = 0; i < 4; ++i) {
            if (redb[i] > bb) bb = redb[i];
            ss += reds[i];
        }
        psum[b * NBKT + bkt] = ss;
        pcnt[b * NBKT + bkt] = e - s;
        if (bb) atomicMax(&best[b * NUM_C + c], bb);
    }
}

// 128 threads, one per (b,c): fold 64 range-buckets, decode mode,
// out = sum_{b,c}(sum - cnt*mode) / (B*N).
__global__ void __launch_bounds__(128)
finalize_kernel(const double* __restrict__ psum,
                const unsigned* __restrict__ pcnt,
                const unsigned long long* __restrict__ best,
                float* __restrict__ out, double inv_total)
{
    __shared__ double acc[NUM_B * NUM_C];
    const int i = threadIdx.x;
    const int b = i >> 4, c = i & 15;

    double s = 0.0;
    unsigned long long cnt = 0ull;
    const double*   ps = psum + (size_t)b * NBKT + ((size_t)c << 6);
    const unsigned* pc = pcnt + (size_t)b * NBKT + ((size_t)c << 6);
    for (int r = 0; r < RANGES; ++r) { s += ps[r]; cnt += pc[r]; }

    double term = 0.0;
    if (cnt > 0ull) {
        unsigned long long p = best[i];
        unsigned ord = 0xFFFFFFFFu - (unsigned)(p & 0xFFFFFFFFull);
        unsigned ub  = (ord & 0x80000000u) ? (ord ^ 0x80000000u) : ~ord;
        float mode = __uint_as_float(ub);
        term = s - (double)cnt * (double)mode;
    }
    acc[i] = term;
    __syncthreads();
    for (int st = 64; st > 0; st >>= 1) {
        if (i < st) acc[i] += acc[i + st];
        __syncthreads();
    }
    if (i == 0) out[0] = (float)(acc[0] * inv_total);
}

extern "C" void kernel_launch(void* const* d_in, const int* in_sizes, int n_in,
                              void* d_out, int out_size, void* d_ws, size_t ws_size,
                              hipStream_t stream)
{
    const float* x = (const float*)d_in[0];
    const int*   t = (const int*)d_in[1];

    const long long total = in_sizes[0];
    const long long N = total / NUM_B;
    const int nblk = (int)((N + CHUNK - 1) / CHUNK);   // 489 for N=2M (<=512)

    // Fixed workspace: best 1K | psum 64K | pcnt 32K | totals | then per-batch
    char* ws = (char*)d_ws;
    size_t off = 0;
    unsigned long long* best = (unsigned long long*)(ws + off);
    off += (size_t)NUM_B * NUM_C * 8;
    double* psum = (double*)(ws + off);
    off += (size_t)NUM_B * NBKT * 8;
    unsigned* pcnt = (unsigned*)(ws + off);
    off += (size_t)NUM_B * NBKT * 4;
    unsigned* totals = (unsigned*)(ws + off);
    off += (size_t)MAX_NB * NBKT * 4;
    off = (off + 255) & ~(size_t)255;

    const size_t meta_per_b = (size_t)nblk * NBKT;     // counts/countsT/goff
    const size_t per_b = (size_t)N * 4 + 3 * meta_per_b * 4 + (NBKT + 1) * 4 + 256;
    size_t remaining = ws_size - off;
    int nb = (int)(remaining / per_b);
    if (nb < 1) nb = 1;
    if (nb > MAX_NB) nb = MAX_NB;

    unsigned* keysout = (unsigned*)(ws + off);
    off += (size_t)nb * N * 4;
    unsigned* counts  = (unsigned*)(ws + off);
    off += (size_t)nb * meta_per_b * 4;
    unsigned* countsT = (unsigned*)(ws + off);
    off += (size_t)nb * meta_per_b * 4;
    unsigned* goff    = (unsigned*)(ws + off);
    off += (size_t)nb * meta_per_b * 4;
    unsigned* baseA   = (unsigned*)(ws + off);

    hipMemsetAsync(best, 0, (size_t)NUM_B * NUM_C * 8, stream);
    for (int r = 0; r < NUM_B; r += nb) {
        const int nbr = (NUM_B - r < nb) ? (NUM_B - r) : nb;
        dim3 tg((nblk + 31) / 32, NBKT / 32, nbr);
        hist_kernel<<<nbr * nblk, 256, 0, stream>>>(x, t, N, r, nblk, counts);
        transpose_kernel<<<tg, 256, 0, stream>>>(counts, countsT, nblk);
        rowscan_kernel<<<nbr * NBKT, 256, 0, stream>>>(countsT, totals, nblk);
        basescan_kernel<<<nbr, 256, 0, stream>>>(totals, baseA);
        addt_kernel<<<tg, 256, 0, stream>>>(countsT, baseA, goff, nblk);
        scatter_kernel<<<nbr * nblk, 256, 0, stream>>>(
            x, t, N, r, nblk, counts, goff, keysout);
        mode_kernel<<<nbr * NBKT, 256, 0, stream>>>(
            keysout, baseA, N, r, best, psum, pcnt);
    }
    finalize_kernel<<<1, 128, 0, stream>>>(
        psum, pcnt, best, (float*)d_out,
        1.0 / ((double)NUM_B * (double)N));
}

// Round 7
// 426.354 us; speedup vs baseline: 1.0325x; 1.0325x over previous
//
#include <hip/hip_runtime.h>
#include <stdint.h>

#define NUM_C 16
#define NUM_B 8
#define RANGES 64                        // hash sub-ranges per class
#define NBKT (NUM_C * RANGES)            // 1024 buckets per batch
#define CHUNK 4096                       // items per scatter chunk
#define TAB_SLOTS 4096                   // LDS hash slots (load ~0.48)
#define MAX_NB 4                         // batches per round (ws-adaptive)

__device__ __forceinline__ unsigned hash_u32(unsigned h) {
    h ^= h >> 16; h *= 0x85ebca6bu;
    h ^= h >> 13; h *= 0xc2b2ae35u;
    h ^= h >> 16;
    return h;
}
__device__ __forceinline__ unsigned canon_key(float v) {
    unsigned k = __float_as_uint(v);
    return (k == 0x80000000u) ? 0u : k;          // -0.0 == +0.0
}
__device__ __forceinline__ unsigned bucket_of(unsigned key, int c) {
    return ((unsigned)c << 6) | (hash_u32(key) >> 26);
}

// K1: per-chunk bucket histogram -> counts[lb][seg][bkt] (coalesced write).
__global__ void __launch_bounds__(256)
hist_kernel(const float* __restrict__ x, const int* __restrict__ t,
            long long N, int bbase, int nblk,
            unsigned* __restrict__ counts)
{
    __shared__ unsigned hist[NBKT];
    const int lb  = blockIdx.x / nblk;
    const int blk = blockIdx.x % nblk;
    const int b   = bbase + lb;
    const long long base = (long long)blk * CHUNK;
    const int count = (int)((N - base < CHUNK) ? (N - base) : CHUNK);
    const float* xb = x + (size_t)b * N + base;
    const int*   tb = t + (size_t)b * N + base;

    for (int i = threadIdx.x; i < NBKT; i += 256) hist[i] = 0u;
    __syncthreads();

    const bool vec_ok = ((N & 3) == 0);
    const int n4 = vec_ok ? (count >> 2) : 0;
    for (int i = threadIdx.x; i < n4; i += 256) {
        float4 v  = ((const float4*)xb)[i];
        int4   cc = ((const int4*)tb)[i];
        atomicAdd(&hist[bucket_of(canon_key(v.x), cc.x)], 1u);
        atomicAdd(&hist[bucket_of(canon_key(v.y), cc.y)], 1u);
        atomicAdd(&hist[bucket_of(canon_key(v.z), cc.z)], 1u);
        atomicAdd(&hist[bucket_of(canon_key(v.w), cc.w)], 1u);
    }
    for (int i = (n4 << 2) + threadIdx.x; i < count; i += 256)
        atomicAdd(&hist[bucket_of(canon_key(xb[i]), tb[i])], 1u);
    __syncthreads();

    unsigned* og = counts + ((size_t)lb * nblk + blk) * NBKT;
    for (int i = threadIdx.x; i < NBKT; i += 256) og[i] = hist[i];
}

// K2: transpose counts [seg][bkt] -> countsT [bkt][seg].
__global__ void __launch_bounds__(256)
transpose_kernel(const unsigned* __restrict__ src_, unsigned* __restrict__ dst_,
                 int nblk)
{
    __shared__ unsigned tile[32][33];
    const int lb   = blockIdx.z;
    const int seg0 = blockIdx.x * 32;
    const int bkt0 = blockIdx.y * 32;
    const unsigned* src = src_ + (size_t)lb * nblk * NBKT;
    unsigned*       dst = dst_ + (size_t)lb * nblk * NBKT;
    const int tx = threadIdx.x & 31, ty = threadIdx.x >> 5;
    #pragma unroll
    for (int j = 0; j < 32; j += 8) {
        int seg = seg0 + ty + j;
        if (seg < nblk) tile[ty + j][tx] = src[(size_t)seg * NBKT + bkt0 + tx];
    }
    __syncthreads();
    #pragma unroll
    for (int j = 0; j < 32; j += 8) {
        if (seg0 + tx < nblk)
            dst[(size_t)(bkt0 + ty + j) * nblk + seg0 + tx] = tile[tx][ty + j];
    }
}

// K3: per-bucket exclusive scan across chunks (in place on countsT row),
// bucket total -> totals[lb][bkt].  Requires nblk <= 512.
__global__ void __launch_bounds__(256)
rowscan_kernel(unsigned* __restrict__ countsT, unsigned* __restrict__ totals,
               int nblk)
{
    __shared__ unsigned a[512];
    unsigned* row = countsT + (size_t)blockIdx.x * nblk;
    const int tid = threadIdx.x;
    a[tid]       = (tid < nblk)       ? row[tid]       : 0u;
    a[tid + 256] = (tid + 256 < nblk) ? row[tid + 256] : 0u;
    __syncthreads();
    for (int st = 1; st < 512; st <<= 1) {
        unsigned v0 = a[tid]       + ((tid >= st)       ? a[tid - st]       : 0u);
        unsigned v1 = a[tid + 256] + ((tid + 256 >= st) ? a[tid + 256 - st] : 0u);
        __syncthreads();
        a[tid] = v0; a[tid + 256] = v1;
        __syncthreads();
    }
    if (tid < nblk)       row[tid]       = tid ? a[tid - 1] : 0u;
    if (tid + 256 < nblk) row[tid + 256] = a[tid + 255];
    if (tid == 0) totals[blockIdx.x] = a[511];
}

// K4: per-batch exclusive scan of 1024 bucket totals -> base[lb][0..1024]
// (sentinel base[1024] = N).
__global__ void __launch_bounds__(256)
basescan_kernel(const unsigned* __restrict__ totals, unsigned* __restrict__ base)
{
    __shared__ unsigned a[NBKT];
    const int lb = blockIdx.x, tid = threadIdx.x;
    const unsigned* tr = totals + (size_t)lb * NBKT;
    unsigned* br = base + (size_t)lb * (NBKT + 1);
    #pragma unroll
    for (int r = 0; r < 4; ++r) a[tid + r * 256] = tr[tid + r * 256];
    __syncthreads();
    for (int st = 1; st < NBKT; st <<= 1) {
        unsigned v[4];
        #pragma unroll
        for (int r = 0; r < 4; ++r) {
            int k = tid + r * 256;
            v[r] = a[k] + ((k >= st) ? a[k - st] : 0u);
        }
        __syncthreads();
        #pragma unroll
        for (int r = 0; r < 4; ++r) a[tid + r * 256] = v[r];
        __syncthreads();
    }
    #pragma unroll
    for (int r = 0; r < 4; ++r) {
        int k = tid + r * 256;
        br[k] = k ? a[k - 1] : 0u;
    }
    if (tid == 0) br[NBKT] = a[NBKT - 1];
}

// K5: transpose scanned countsT [bkt][seg] back to goff [seg][bkt], + base.
__global__ void __launch_bounds__(256)
addt_kernel(const unsigned* __restrict__ scanned, const unsigned* __restrict__ base,
            unsigned* __restrict__ goff, int nblk)
{
    __shared__ unsigned tile[32][33];
    const int lb   = blockIdx.z;
    const int seg0 = blockIdx.x * 32;
    const int bkt0 = blockIdx.y * 32;
    const unsigned* src = scanned + (size_t)lb * nblk * NBKT;
    const unsigned* br  = base + (size_t)lb * (NBKT + 1);
    unsigned*       dst = goff + (size_t)lb * nblk * NBKT;
    const int tx = threadIdx.x & 31, ty = threadIdx.x >> 5;
    #pragma unroll
    for (int j = 0; j < 32; j += 8) {
        if (seg0 + tx < nblk)
            tile[ty + j][tx] = src[(size_t)(bkt0 + ty + j) * nblk + seg0 + tx];
    }
    __syncthreads();
    #pragma unroll
    for (int j = 0; j < 32; j += 8) {
        int seg = seg0 + ty + j;
        if (seg < nblk)
            dst[(size_t)seg * NBKT + bkt0 + tx] = tile[tx][ty + j] + br[bkt0 + tx];
    }
}

// K6: placement scatter (unchanged from R6). LDS counting sort of the chunk,
// then write each item to its exact globally-bucket-sorted position.
__global__ void __launch_bounds__(256)
scatter_kernel(const float* __restrict__ x, const int* __restrict__ t,
               long long N, int bbase, int nblk,
               const unsigned* __restrict__ counts,
               const unsigned* __restrict__ goff,
               unsigned* __restrict__ keysout)
{
    __shared__ unsigned hist[NBKT];
    __shared__ unsigned sstart[NBKT];
    __shared__ unsigned lout[CHUNK];
    __shared__ unsigned short lbkt[CHUNK];
    __shared__ unsigned sscan[256];

    const int lb  = blockIdx.x / nblk;
    const int blk = blockIdx.x % nblk;
    const int b   = bbase + lb;
    const long long base = (long long)blk * CHUNK;
    const int count = (int)((N - base < CHUNK) ? (N - base) : CHUNK);
    const float* xb = x + (size_t)b * N + base;
    const int*   tb = t + (size_t)b * N + base;
    const unsigned* crow = counts + ((size_t)lb * nblk + blk) * NBKT;
    const unsigned* grow = goff   + ((size_t)lb * nblk + blk) * NBKT;

    for (int i = threadIdx.x; i < NBKT; i += 256) hist[i] = crow[i];
    __syncthreads();

    unsigned h0 = hist[threadIdx.x * 4 + 0];
    unsigned h1 = hist[threadIdx.x * 4 + 1];
    unsigned h2 = hist[threadIdx.x * 4 + 2];
    unsigned h3 = hist[threadIdx.x * 4 + 3];
    unsigned local = h0 + h1 + h2 + h3;
    sscan[threadIdx.x] = local;
    __syncthreads();
    for (int st = 1; st < 256; st <<= 1) {
        unsigned v = (threadIdx.x >= (unsigned)st) ? sscan[threadIdx.x - st] : 0u;
        __syncthreads();
        sscan[threadIdx.x] += v;
        __syncthreads();
    }
    unsigned excl = sscan[threadIdx.x] - local;
    unsigned o0 = excl, o1 = o0 + h0, o2 = o1 + h1, o3 = o2 + h2;
    hist[threadIdx.x * 4 + 0] = o0; sstart[threadIdx.x * 4 + 0] = o0;
    hist[threadIdx.x * 4 + 1] = o1; sstart[threadIdx.x * 4 + 1] = o1;
    hist[threadIdx.x * 4 + 2] = o2; sstart[threadIdx.x * 4 + 2] = o2;
    hist[threadIdx.x * 4 + 3] = o3; sstart[threadIdx.x * 4 + 3] = o3;
    __syncthreads();

    const bool vec_ok = ((N & 3) == 0);
    const int n4 = vec_ok ? (count >> 2) : 0;
    for (int i = threadIdx.x; i < n4; i += 256) {
        float4 v  = ((const float4*)xb)[i];
        int4   cc = ((const int4*)tb)[i];
        unsigned k, bk, p;
        k = canon_key(v.x); bk = bucket_of(k, cc.x);
        p = atomicAdd(&hist[bk], 1u); lout[p] = k; lbkt[p] = (unsigned short)bk;
        k = canon_key(v.y); bk = bucket_of(k, cc.y);
        p = atomicAdd(&hist[bk], 1u); lout[p] = k; lbkt[p] = (unsigned short)bk;
        k = canon_key(v.z); bk = bucket_of(k, cc.z);
        p = atomicAdd(&hist[bk], 1u); lout[p] = k; lbkt[p] = (unsigned short)bk;
        k = canon_key(v.w); bk = bucket_of(k, cc.w);
        p = atomicAdd(&hist[bk], 1u); lout[p] = k; lbkt[p] = (unsigned short)bk;
    }
    for (int i = (n4 << 2) + threadIdx.x; i < count; i += 256) {
        unsigned k = canon_key(xb[i]);
        unsigned bk = bucket_of(k, tb[i]);
        unsigned p = atomicAdd(&hist[bk], 1u);
        lout[p] = k; lbkt[p] = (unsigned short)bk;
    }
    __syncthreads();

    for (int i = threadIdx.x; i < NBKT; i += 256) hist[i] = grow[i] - sstart[i];
    __syncthreads();

    unsigned* kb = keysout + (size_t)lb * N;
    for (int i = threadIdx.x; i < count; i += 256)
        kb[hist[lbkt[i]] + i] = lout[i];
}

// K7: one block per (batch,bucket); bucket is one contiguous run.
// 512 threads + ILP-4 probe state machines: 4 independent ds_read/atomic
// chains in flight per thread. Packed (count<<32 | key) LDS table;
// best = max(count<<32 | (2^32-1 - ord(value))): max count, ties -> min value.
__global__ void __launch_bounds__(512)
mode_kernel(const unsigned* __restrict__ keysout,
            const unsigned* __restrict__ base, long long N, int bbase,
            unsigned long long* __restrict__ best,   // [NUM_B*NUM_C], zeroed
            double* __restrict__ psum,               // [NUM_B*NBKT]
            unsigned* __restrict__ pcnt)             // [NUM_B*NBKT]
{
    __shared__ unsigned long long tab[TAB_SLOTS];    // 32 KiB
    __shared__ unsigned long long redb[8];
    __shared__ double reds[8];

    const unsigned lb  = blockIdx.x / NBKT;
    const unsigned bkt = blockIdx.x % NBKT;
    const unsigned c   = bkt >> 6;
    const unsigned b   = (unsigned)bbase + lb;
    const int tid = threadIdx.x;

    for (int i = tid; i < TAB_SLOTS; i += 512) tab[i] = 0ull;
    __syncthreads();

    const unsigned* br = base + (size_t)lb * (NBKT + 1);
    const unsigned s = br[bkt], e = br[bkt + 1];
    const unsigned* kb = keysout + (size_t)lb * N;

    double ls = 0.0;
    for (unsigned i0 = s + tid; i0 < e; i0 += 2048) {
        unsigned k[4], h[4];
        int rem = 0;
        #pragma unroll
        for (int j = 0; j < 4; ++j) {
            unsigned idx = i0 + (unsigned)j * 512u;
            if (idx < e) {
                unsigned key = kb[idx];              // coalesced
                k[j] = key;
                h[j] = hash_u32(key) & (TAB_SLOTS - 1);
                ls += (double)__uint_as_float(key);
                rem |= 1 << j;
            }
        }
        while (rem) {
            unsigned long long cur[4];
            #pragma unroll
            for (int j = 0; j < 4; ++j)
                if (rem & (1 << j)) cur[j] = tab[h[j]];   // overlapped reads
            #pragma unroll
            for (int j = 0; j < 4; ++j) {
                if (!(rem & (1 << j))) continue;
                unsigned long long cv = cur[j];
                if (cv != 0ull && (unsigned)cv == k[j]) {
                    atomicAdd(&tab[h[j]], 1ull << 32);
                    rem &= ~(1 << j);
                } else if (cv == 0ull) {
                    unsigned long long pk = (1ull << 32)
                                          | (unsigned long long)k[j];
                    unsigned long long old = atomicCAS(&tab[h[j]], 0ull, pk);
                    if (old == 0ull) {
                        rem &= ~(1 << j);
                    } else if ((unsigned)old == k[j]) {
                        atomicAdd(&tab[h[j]], 1ull << 32);
                        rem &= ~(1 << j);
                    } else {
                        h[j] = (h[j] + 1u) & (TAB_SLOTS - 1);
                    }
                } else {
                    h[j] = (h[j] + 1u) & (TAB_SLOTS - 1);
                }
            }
        }
    }
    __syncthreads();

    unsigned long long lbst = 0ull;
    for (int s2 = tid; s2 < TAB_SLOTS; s2 += 512) {
        unsigned long long curv = tab[s2];
        if (curv) {
            unsigned kk  = (unsigned)curv;
            unsigned ct  = (unsigned)(curv >> 32);
            unsigned ord = (kk & 0x80000000u) ? ~kk : (kk | 0x80000000u);
            unsigned long long p = ((unsigned long long)ct << 32)
                                 | (unsigned long long)(0xFFFFFFFFu - ord);
            if (p > lbst) lbst = p;
        }
    }
    #pragma unroll
    for (int sh = 32; sh > 0; sh >>= 1) {
        unsigned long long ob = __shfl_down(lbst, sh);
        if (ob > lbst) lbst = ob;
        ls += __shfl_down(ls, sh);
    }
    const int wid = tid >> 6;
    if ((tid & 63) == 0) { redb[wid] = lbst; reds[wid] = ls; }
    __syncthreads();
    if (tid == 0) {
        unsigned long long bb = 0ull; double ss = 0.0;
        #pragma unroll
        for (int i = 0; i < 8; ++i) {
            if (redb[i] > bb) bb = redb[i];
            ss += reds[i];
        }
        psum[b * NBKT + bkt] = ss;
        pcnt[b * NBKT + bkt] = e - s;
        if (bb) atomicMax(&best[b * NUM_C + c], bb);
    }
}

// 128 threads, one per (b,c): fold 64 range-buckets, decode mode,
// out = sum_{b,c}(sum - cnt*mode) / (B*N).
__global__ void __launch_bounds__(128)
finalize_kernel(const double* __restrict__ psum,
                const unsigned* __restrict__ pcnt,
                const unsigned long long* __restrict__ best,
                float* __restrict__ out, double inv_total)
{
    __shared__ double acc[NUM_B * NUM_C];
    const int i = threadIdx.x;
    const int b = i >> 4, c = i & 15;

    double s = 0.0;
    unsigned long long cnt = 0ull;
    const double*   ps = psum + (size_t)b * NBKT + ((size_t)c << 6);
    const unsigned* pc = pcnt + (size_t)b * NBKT + ((size_t)c << 6);
    for (int r = 0; r < RANGES; ++r) { s += ps[r]; cnt += pc[r]; }

    double term = 0.0;
    if (cnt > 0ull) {
        unsigned long long p = best[i];
        unsigned ord = 0xFFFFFFFFu - (unsigned)(p & 0xFFFFFFFFull);
        unsigned ub  = (ord & 0x80000000u) ? (ord ^ 0x80000000u) : ~ord;
        float mode = __uint_as_float(ub);
        term = s - (double)cnt * (double)mode;
    }
    acc[i] = term;
    __syncthreads();
    for (int st = 64; st > 0; st >>= 1) {
        if (i < st) acc[i] += acc[i + st];
        __syncthreads();
    }
    if (i == 0) out[0] = (float)(acc[0] * inv_total);
}

extern "C" void kernel_launch(void* const* d_in, const int* in_sizes, int n_in,
                              void* d_out, int out_size, void* d_ws, size_t ws_size,
                              hipStream_t stream)
{
    const float* x = (const float*)d_in[0];
    const int*   t = (const int*)d_in[1];

    const long long total = in_sizes[0];
    const long long N = total / NUM_B;
    const int nblk = (int)((N + CHUNK - 1) / CHUNK);   // 489 for N=2M (<=512)

    char* ws = (char*)d_ws;
    size_t off = 0;
    unsigned long long* best = (unsigned long long*)(ws + off);
    off += (size_t)NUM_B * NUM_C * 8;
    double* psum = (double*)(ws + off);
    off += (size_t)NUM_B * NBKT * 8;
    unsigned* pcnt = (unsigned*)(ws + off);
    off += (size_t)NUM_B * NBKT * 4;
    unsigned* totals = (unsigned*)(ws + off);
    off += (size_t)MAX_NB * NBKT * 4;
    off = (off + 255) & ~(size_t)255;

    const size_t meta_per_b = (size_t)nblk * NBKT;     // counts/countsT/goff
    const size_t per_b = (size_t)N * 4 + 3 * meta_per_b * 4 + (NBKT + 1) * 4 + 256;
    size_t remaining = ws_size - off;
    int nb = (int)(remaining / per_b);
    if (nb < 1) nb = 1;
    if (nb > MAX_NB) nb = MAX_NB;

    unsigned* keysout = (unsigned*)(ws + off);
    off += (size_t)nb * N * 4;
    unsigned* counts  = (unsigned*)(ws + off);
    off += (size_t)nb * meta_per_b * 4;
    unsigned* countsT = (unsigned*)(ws + off);
    off += (size_t)nb * meta_per_b * 4;
    unsigned* goff    = (unsigned*)(ws + off);
    off += (size_t)nb * meta_per_b * 4;
    unsigned* baseA   = (unsigned*)(ws + off);

    hipMemsetAsync(best, 0, (size_t)NUM_B * NUM_C * 8, stream);
    for (int r = 0; r < NUM_B; r += nb) {
        const int nbr = (NUM_B - r < nb) ? (NUM_B - r) : nb;
        dim3 tg((nblk + 31) / 32, NBKT / 32, nbr);
        hist_kernel<<<nbr * nblk, 256, 0, stream>>>(x, t, N, r, nblk, counts);
        transpose_kernel<<<tg, 256, 0, stream>>>(counts, countsT, nblk);
        rowscan_kernel<<<nbr * NBKT, 256, 0, stream>>>(countsT, totals, nblk);
        basescan_kernel<<<nbr, 256, 0, stream>>>(totals, baseA);
        addt_kernel<<<tg, 256, 0, stream>>>(countsT, baseA, goff, nblk);
        scatter_kernel<<<nbr * nblk, 256, 0, stream>>>(
            x, t, N, r, nblk, counts, goff, keysout);
        mode_kernel<<<nbr * NBKT, 512, 0, stream>>>(
            keysout, baseA, N, r, best, psum, pcnt);
    }
    finalize_kernel<<<1, 128, 0, stream>>>(
        psum, pcnt, best, (float*)d_out,
        1.0 / ((double)NUM_B * (double)N));
}

// Round 8
// 365.233 us; speedup vs baseline: 1.2053x; 1.1673x over previous
//
#include <hip/hip_runtime.h>
#include <stdint.h>

#define NUM_C 16
#define NUM_B 8
#define RANGES 64                        // hash sub-ranges per class
#define NBKT (NUM_C * RANGES)            // 1024 buckets per batch
#define CHUNK 4096                       // items per scatter chunk
#define TAB_SLOTS 4096                   // LDS hash slots (load ~0.48)
#define MAX_NB 8                         // batches per round (ws-adaptive)
#define SCAN_BKT 16                      // buckets per rowscanT block

__device__ __forceinline__ unsigned hash_u32(unsigned h) {
    h ^= h >> 16; h *= 0x85ebca6bu;
    h ^= h >> 13; h *= 0xc2b2ae35u;
    h ^= h >> 16;
    return h;                            // invertible (xorshift-mul) mixer
}
__device__ __forceinline__ unsigned canon_key(float v) {
    unsigned k = __float_as_uint(v);
    return (k == 0x80000000u) ? 0u : k;  // -0.0 == +0.0
}
__device__ __forceinline__ unsigned bucket_of(unsigned key, int c) {
    return ((unsigned)c << 6) | (hash_u32(key) >> 26);
}

// K1: per-chunk bucket histogram -> counts[lb][seg][bkt] (coalesced write).
__global__ void __launch_bounds__(256)
hist_kernel(const float* __restrict__ x, const int* __restrict__ t,
            long long N, int bbase, int nblk,
            unsigned* __restrict__ counts)
{
    __shared__ unsigned hist[NBKT];
    const int lb  = blockIdx.x / nblk;
    const int blk = blockIdx.x % nblk;
    const int b   = bbase + lb;
    const long long base = (long long)blk * CHUNK;
    const int count = (int)((N - base < CHUNK) ? (N - base) : CHUNK);
    const float* xb = x + (size_t)b * N + base;
    const int*   tb = t + (size_t)b * N + base;

    for (int i = threadIdx.x; i < NBKT; i += 256) hist[i] = 0u;
    __syncthreads();

    const bool vec_ok = ((N & 3) == 0);
    const int n4 = vec_ok ? (count >> 2) : 0;
    for (int i = threadIdx.x; i < n4; i += 256) {
        float4 v  = ((const float4*)xb)[i];
        int4   cc = ((const int4*)tb)[i];
        atomicAdd(&hist[bucket_of(canon_key(v.x), cc.x)], 1u);
        atomicAdd(&hist[bucket_of(canon_key(v.y), cc.y)], 1u);
        atomicAdd(&hist[bucket_of(canon_key(v.z), cc.z)], 1u);
        atomicAdd(&hist[bucket_of(canon_key(v.w), cc.w)], 1u);
    }
    for (int i = (n4 << 2) + threadIdx.x; i < count; i += 256)
        atomicAdd(&hist[bucket_of(canon_key(xb[i]), tb[i])], 1u);
    __syncthreads();

    unsigned* og = counts + ((size_t)lb * nblk + blk) * NBKT;
    for (int i = threadIdx.x; i < NBKT; i += 256) og[i] = hist[i];
}

// K2 (fused transpose+scan): per 16-bucket group, load counts column tile,
// exclusive-scan each bucket across chunks, write goff[seg][bkt] (WITHOUT
// per-batch base -- scatter adds base itself) and bucket totals.
// Requires nblk <= 512.
__global__ void __launch_bounds__(256)
rowscanT_kernel(const unsigned* __restrict__ counts,
                unsigned* __restrict__ goff,
                unsigned* __restrict__ totals, int nblk)
{
    __shared__ unsigned tile[512][SCAN_BKT];     // 32 KiB
    __shared__ unsigned part[16][SCAN_BKT];
    const int nbg  = NBKT / SCAN_BKT;            // 64
    const int lb   = blockIdx.x / nbg;
    const int bkt0 = (blockIdx.x % nbg) * SCAN_BKT;
    const int tx = threadIdx.x & 15;             // bucket lane
    const int ty = threadIdx.x >> 4;             // seg group 0..15

    const unsigned* cb = counts + (size_t)lb * nblk * NBKT;
    for (int seg = ty; seg < 512; seg += 16)
        tile[seg][tx] = (seg < nblk) ? cb[(size_t)seg * NBKT + bkt0 + tx] : 0u;
    __syncthreads();

    unsigned s = 0;
    #pragma unroll 8
    for (int j = 0; j < 32; ++j) s += tile[ty * 32 + j][tx];
    part[ty][tx] = s;
    __syncthreads();

    if (ty == 0) {                               // 16 threads: scan partials
        unsigned run = 0;
        #pragma unroll
        for (int j = 0; j < 16; ++j) {
            unsigned v = part[j][tx]; part[j][tx] = run; run += v;
        }
        totals[(size_t)lb * NBKT + bkt0 + tx] = run;
    }
    __syncthreads();

    unsigned run = part[ty][tx];
    unsigned* gb = goff + (size_t)lb * nblk * NBKT;
    for (int j = 0; j < 32; ++j) {
        int seg = ty * 32 + j;
        unsigned v = tile[seg][tx];
        if (seg < nblk) gb[(size_t)seg * NBKT + bkt0 + tx] = run;
        run += v;
    }
}

// K3: per-batch exclusive scan of 1024 bucket totals -> base[lb][0..1024]
// (sentinel base[1024] = N).
__global__ void __launch_bounds__(256)
basescan_kernel(const unsigned* __restrict__ totals, unsigned* __restrict__ base)
{
    __shared__ unsigned a[NBKT];
    const int lb = blockIdx.x, tid = threadIdx.x;
    const unsigned* tr = totals + (size_t)lb * NBKT;
    unsigned* br = base + (size_t)lb * (NBKT + 1);
    #pragma unroll
    for (int r = 0; r < 4; ++r) a[tid + r * 256] = tr[tid + r * 256];
    __syncthreads();
    for (int st = 1; st < NBKT; st <<= 1) {
        unsigned v[4];
        #pragma unroll
        for (int r = 0; r < 4; ++r) {
            int k = tid + r * 256;
            v[r] = a[k] + ((k >= st) ? a[k - st] : 0u);
        }
        __syncthreads();
        #pragma unroll
        for (int r = 0; r < 4; ++r) a[tid + r * 256] = v[r];
        __syncthreads();
    }
    #pragma unroll
    for (int r = 0; r < 4; ++r) {
        int k = tid + r * 256;
        br[k] = k ? a[k - 1] : 0u;
    }
    if (tid == 0) br[NBKT] = a[NBKT - 1];
}

// K4: placement scatter. LDS counting sort of the chunk, then write each
// item to its exact globally-bucket-sorted position (runs -> consecutive
// addresses). Global run start = goff (chunk-exclusive) + base (bucket).
__global__ void __launch_bounds__(256)
scatter_kernel(const float* __restrict__ x, const int* __restrict__ t,
               long long N, int bbase, int nblk,
               const unsigned* __restrict__ counts,
               const unsigned* __restrict__ goff,
               const unsigned* __restrict__ base,
               unsigned* __restrict__ keysout)
{
    __shared__ unsigned hist[NBKT];
    __shared__ unsigned sstart[NBKT];
    __shared__ unsigned lout[CHUNK];
    __shared__ unsigned short lbkt[CHUNK];
    __shared__ unsigned sscan[256];

    const int lb  = blockIdx.x / nblk;
    const int blk = blockIdx.x % nblk;
    const int b   = bbase + lb;
    const long long gbase = (long long)blk * CHUNK;
    const int count = (int)((N - gbase < CHUNK) ? (N - gbase) : CHUNK);
    const float* xb = x + (size_t)b * N + gbase;
    const int*   tb = t + (size_t)b * N + gbase;
    const unsigned* crow = counts + ((size_t)lb * nblk + blk) * NBKT;
    const unsigned* grow = goff   + ((size_t)lb * nblk + blk) * NBKT;
    const unsigned* br   = base + (size_t)lb * (NBKT + 1);

    for (int i = threadIdx.x; i < NBKT; i += 256) hist[i] = crow[i];
    __syncthreads();

    unsigned h0 = hist[threadIdx.x * 4 + 0];
    unsigned h1 = hist[threadIdx.x * 4 + 1];
    unsigned h2 = hist[threadIdx.x * 4 + 2];
    unsigned h3 = hist[threadIdx.x * 4 + 3];
    unsigned local = h0 + h1 + h2 + h3;
    sscan[threadIdx.x] = local;
    __syncthreads();
    for (int st = 1; st < 256; st <<= 1) {
        unsigned v = (threadIdx.x >= (unsigned)st) ? sscan[threadIdx.x - st] : 0u;
        __syncthreads();
        sscan[threadIdx.x] += v;
        __syncthreads();
    }
    unsigned excl = sscan[threadIdx.x] - local;
    unsigned o0 = excl, o1 = o0 + h0, o2 = o1 + h1, o3 = o2 + h2;
    hist[threadIdx.x * 4 + 0] = o0; sstart[threadIdx.x * 4 + 0] = o0;
    hist[threadIdx.x * 4 + 1] = o1; sstart[threadIdx.x * 4 + 1] = o1;
    hist[threadIdx.x * 4 + 2] = o2; sstart[threadIdx.x * 4 + 2] = o2;
    hist[threadIdx.x * 4 + 3] = o3; sstart[threadIdx.x * 4 + 3] = o3;
    __syncthreads();

    const bool vec_ok = ((N & 3) == 0);
    const int n4 = vec_ok ? (count >> 2) : 0;
    for (int i = threadIdx.x; i < n4; i += 256) {
        float4 v  = ((const float4*)xb)[i];
        int4   cc = ((const int4*)tb)[i];
        unsigned k, bk, p;
        k = canon_key(v.x); bk = bucket_of(k, cc.x);
        p = atomicAdd(&hist[bk], 1u); lout[p] = k; lbkt[p] = (unsigned short)bk;
        k = canon_key(v.y); bk = bucket_of(k, cc.y);
        p = atomicAdd(&hist[bk], 1u); lout[p] = k; lbkt[p] = (unsigned short)bk;
        k = canon_key(v.z); bk = bucket_of(k, cc.z);
        p = atomicAdd(&hist[bk], 1u); lout[p] = k; lbkt[p] = (unsigned short)bk;
        k = canon_key(v.w); bk = bucket_of(k, cc.w);
        p = atomicAdd(&hist[bk], 1u); lout[p] = k; lbkt[p] = (unsigned short)bk;
    }
    for (int i = (n4 << 2) + threadIdx.x; i < count; i += 256) {
        unsigned k = canon_key(xb[i]);
        unsigned bk = bucket_of(k, tb[i]);
        unsigned p = atomicAdd(&hist[bk], 1u);
        lout[p] = k; lbkt[p] = (unsigned short)bk;
    }
    __syncthreads();

    // delta = global run start - local run start
    for (int i = threadIdx.x; i < NBKT; i += 256)
        hist[i] = grow[i] + br[i] - sstart[i];
    __syncthreads();

    unsigned* kb = keysout + (size_t)lb * N;
    for (int i = threadIdx.x; i < count; i += 256)
        kb[hist[lbkt[i]] + i] = lout[i];
}

// K5: one block per (batch,bucket); bucket is one contiguous run.
// CAS-first insert (1 LDS op on the hot path), ILP-4 state machines,
// b128 clear/scan. Packed (count<<32 | key) LDS table; best =
// max(count<<32 | (2^32-1 - ord(value))): max count, ties -> min value.
__global__ void __launch_bounds__(512)
mode_kernel(const unsigned* __restrict__ keysout,
            const unsigned* __restrict__ base, long long N, int bbase,
            unsigned long long* __restrict__ best,   // [NUM_B*NUM_C], zeroed
            double* __restrict__ psum,               // [NUM_B*NBKT]
            unsigned* __restrict__ pcnt)             // [NUM_B*NBKT]
{
    __shared__ unsigned long long tab[TAB_SLOTS];    // 32 KiB
    __shared__ unsigned long long redb[8];
    __shared__ double reds[8];

    const unsigned lb  = blockIdx.x / NBKT;
    const unsigned bkt = blockIdx.x % NBKT;
    const unsigned c   = bkt >> 6;
    const unsigned b   = (unsigned)bbase + lb;
    const int tid = threadIdx.x;

    uint4* t4 = (uint4*)tab;                         // 2048 uint4
    const uint4 z4 = make_uint4(0u, 0u, 0u, 0u);
    for (int i = tid; i < TAB_SLOTS / 2; i += 512) t4[i] = z4;
    __syncthreads();

    const unsigned* br = base + (size_t)lb * (NBKT + 1);
    const unsigned s = br[bkt], e = br[bkt + 1];
    const unsigned* kb = keysout + (size_t)lb * N;

    double ls = 0.0;
    for (unsigned i0 = s + tid; i0 < e; i0 += 2048) {
        unsigned k[4], h[4];
        int rem = 0;
        #pragma unroll
        for (int j = 0; j < 4; ++j) {
            unsigned idx = i0 + (unsigned)j * 512u;
            if (idx < e) {
                unsigned key = kb[idx];              // coalesced
                k[j] = key;
                h[j] = hash_u32(key) & (TAB_SLOTS - 1);
                ls += (double)__uint_as_float(key);
                rem |= 1 << j;
            }
        }
        while (rem) {
            unsigned long long old[4];
            #pragma unroll
            for (int j = 0; j < 4; ++j)
                if (rem & (1 << j))
                    old[j] = atomicCAS(&tab[h[j]], 0ull,
                                       (1ull << 32) | (unsigned long long)k[j]);
            #pragma unroll
            for (int j = 0; j < 4; ++j) {
                if (!(rem & (1 << j))) continue;
                if (old[j] == 0ull) {                        // claimed fresh
                    rem &= ~(1 << j);
                } else if ((unsigned)old[j] == k[j]) {       // duplicate
                    atomicAdd(&tab[h[j]], 1ull << 32);
                    rem &= ~(1 << j);
                } else {                                     // occupied-other
                    h[j] = (h[j] + 1u) & (TAB_SLOTS - 1);
                }
            }
        }
    }
    __syncthreads();

    unsigned long long lbst = 0ull;
    for (int i = tid; i < TAB_SLOTS / 2; i += 512) {
        uint4 v = ((const uint4*)tab)[i];            // two slots per read
        if (v.y | v.x) {                             // slot0: key=x count=y
            unsigned ord = (v.x & 0x80000000u) ? ~v.x : (v.x | 0x80000000u);
            unsigned long long p = ((unsigned long long)v.y << 32)
                                 | (unsigned long long)(0xFFFFFFFFu - ord);
            if (p > lbst) lbst = p;
        }
        if (v.w | v.z) {                             // slot1: key=z count=w
            unsigned ord = (v.z & 0x80000000u) ? ~v.z : (v.z | 0x80000000u);
            unsigned long long p = ((unsigned long long)v.w << 32)
                                 | (unsigned long long)(0xFFFFFFFFu - ord);
            if (p > lbst) lbst = p;
        }
    }
    #pragma unroll
    for (int sh = 32; sh > 0; sh >>= 1) {
        unsigned long long ob = __shfl_down(lbst, sh);
        if (ob > lbst) lbst = ob;
        ls += __shfl_down(ls, sh);
    }
    const int wid = tid >> 6;
    if ((tid & 63) == 0) { redb[wid] = lbst; reds[wid] = ls; }
    __syncthreads();
    if (tid == 0) {
        unsigned long long bb = 0ull; double ss = 0.0;
        #pragma unroll
        for (int i = 0; i < 8; ++i) {
            if (redb[i] > bb) bb = redb[i];
            ss += reds[i];
        }
        psum[b * NBKT + bkt] = ss;
        pcnt[b * NBKT + bkt] = e - s;
        if (bb) atomicMax(&best[b * NUM_C + c], bb);
    }
}

// 128 threads, one per (b,c): fold 64 range-buckets, decode mode,
// out = sum_{b,c}(sum - cnt*mode) / (B*N).
__global__ void __launch_bounds__(128)
finalize_kernel(const double* __restrict__ psum,
                const unsigned* __restrict__ pcnt,
                const unsigned long long* __restrict__ best,
                float* __restrict__ out, double inv_total)
{
    __shared__ double acc[NUM_B * NUM_C];
    const int i = threadIdx.x;
    const int b = i >> 4, c = i & 15;

    double s = 0.0;
    unsigned long long cnt = 0ull;
    const double*   ps = psum + (size_t)b * NBKT + ((size_t)c << 6);
    const unsigned* pc = pcnt + (size_t)b * NBKT + ((size_t)c << 6);
    for (int r = 0; r < RANGES; ++r) { s += ps[r]; cnt += pc[r]; }

    double term = 0.0;
    if (cnt > 0ull) {
        unsigned long long p = best[i];
        unsigned ord = 0xFFFFFFFFu - (unsigned)(p & 0xFFFFFFFFull);
        unsigned ub  = (ord & 0x80000000u) ? (ord ^ 0x80000000u) : ~ord;
        float mode = __uint_as_float(ub);
        term = s - (double)cnt * (double)mode;
    }
    acc[i] = term;
    __syncthreads();
    for (int st = 64; st > 0; st >>= 1) {
        if (i < st) acc[i] += acc[i + st];
        __syncthreads();
    }
    if (i == 0) out[0] = (float)(acc[0] * inv_total);
}

extern "C" void kernel_launch(void* const* d_in, const int* in_sizes, int n_in,
                              void* d_out, int out_size, void* d_ws, size_t ws_size,
                              hipStream_t stream)
{
    const float* x = (const float*)d_in[0];
    const int*   t = (const int*)d_in[1];

    const long long total = in_sizes[0];
    const long long N = total / NUM_B;
    const int nblk = (int)((N + CHUNK - 1) / CHUNK);   // 489 for N=2M (<=512)

    char* ws = (char*)d_ws;
    size_t off = 0;
    unsigned long long* best = (unsigned long long*)(ws + off);
    off += (size_t)NUM_B * NUM_C * 8;
    double* psum = (double*)(ws + off);
    off += (size_t)NUM_B * NBKT * 8;
    unsigned* pcnt = (unsigned*)(ws + off);
    off += (size_t)NUM_B * NBKT * 4;
    unsigned* totals = (unsigned*)(ws + off);
    off += (size_t)MAX_NB * NBKT * 4;
    off = (off + 255) & ~(size_t)255;

    const size_t meta_per_b = (size_t)nblk * NBKT;     // counts / goff
    const size_t per_b = (size_t)N * 4 + 2 * meta_per_b * 4 + (NBKT + 1) * 4 + 256;
    size_t remaining = ws_size - off;
    int nb = (int)(remaining / per_b);
    if (nb < 1) nb = 1;
    if (nb > MAX_NB) nb = MAX_NB;

    unsigned* keysout = (unsigned*)(ws + off);
    off += (size_t)nb * N * 4;
    unsigned* counts  = (unsigned*)(ws + off);
    off += (size_t)nb * meta_per_b * 4;
    unsigned* goff    = (unsigned*)(ws + off);
    off += (size_t)nb * meta_per_b * 4;
    unsigned* baseA   = (unsigned*)(ws + off);

    hipMemsetAsync(best, 0, (size_t)NUM_B * NUM_C * 8, stream);
    for (int r = 0; r < NUM_B; r += nb) {
        const int nbr = (NUM_B - r < nb) ? (NUM_B - r) : nb;
        hist_kernel<<<nbr * nblk, 256, 0, stream>>>(x, t, N, r, nblk, counts);
        rowscanT_kernel<<<nbr * (NBKT / SCAN_BKT), 256, 0, stream>>>(
            counts, goff, totals, nblk);
        basescan_kernel<<<nbr, 256, 0, stream>>>(totals, baseA);
        scatter_kernel<<<nbr * nblk, 256, 0, stream>>>(
            x, t, N, r, nblk, counts, goff, baseA, keysout);
        mode_kernel<<<nbr * NBKT, 512, 0, stream>>>(
            keysout, baseA, N, r, best, psum, pcnt);
    }
    finalize_kernel<<<1, 128, 0, stream>>>(
        psum, pcnt, best, (float*)d_out,
        1.0 / ((double)NUM_B * (double)N));
}

// Round 9
// 346.985 us; speedup vs baseline: 1.2687x; 1.0526x over previous
//
#include <hip/hip_runtime.h>
#include <stdint.h>

#define NUM_C 16
#define NUM_B 8
#define RANGES 64                        // hash sub-ranges per class
#define NBKT (NUM_C * RANGES)            // 1024 buckets per batch
#define CHUNK 4096                       // items per scatter chunk
#define TAB_SLOTS 4096                   // LDS hash slots (load ~0.48)
#define MAX_NB 8                         // batches per round (ws-adaptive)
#define SCAN_BKT 16                      // buckets per rowscanT block

__device__ __forceinline__ unsigned hash_u32(unsigned h) {
    h ^= h >> 16; h *= 0x85ebca6bu;
    h ^= h >> 13; h *= 0xc2b2ae35u;
    h ^= h >> 16;
    return h;                            // invertible (xorshift-mul) mixer
}
__device__ __forceinline__ unsigned canon_key(float v) {
    unsigned k = __float_as_uint(v);
    return (k == 0x80000000u) ? 0u : k;  // -0.0 == +0.0
}
__device__ __forceinline__ unsigned bucket_of(unsigned key, int c) {
    return ((unsigned)c << 6) | (hash_u32(key) >> 26);
}

// K1: per-chunk bucket histogram -> counts[lb][seg][bkt]; also emits packed
// uchar labels (t8) so the scatter pass re-reads 1B/label instead of 4B.
__global__ void __launch_bounds__(256)
hist_kernel(const float* __restrict__ x, const int* __restrict__ t,
            long long N, int bbase, int nblk,
            unsigned* __restrict__ counts, unsigned char* __restrict__ t8)
{
    __shared__ unsigned hist[NBKT];
    const int lb  = blockIdx.x / nblk;
    const int blk = blockIdx.x % nblk;
    const int b   = bbase + lb;
    const long long base = (long long)blk * CHUNK;
    const int count = (int)((N - base < CHUNK) ? (N - base) : CHUNK);
    const float* xb = x + (size_t)b * N + base;
    const int*   tb = t + (size_t)b * N + base;
    unsigned char* t8b = t8 + (size_t)lb * N + base;

    for (int i = threadIdx.x; i < NBKT; i += 256) hist[i] = 0u;
    __syncthreads();

    const bool vec_ok = ((N & 3) == 0);
    const int n4 = vec_ok ? (count >> 2) : 0;
    for (int i = threadIdx.x; i < n4; i += 256) {
        float4 v  = ((const float4*)xb)[i];
        int4   cc = ((const int4*)tb)[i];
        atomicAdd(&hist[bucket_of(canon_key(v.x), cc.x)], 1u);
        atomicAdd(&hist[bucket_of(canon_key(v.y), cc.y)], 1u);
        atomicAdd(&hist[bucket_of(canon_key(v.z), cc.z)], 1u);
        atomicAdd(&hist[bucket_of(canon_key(v.w), cc.w)], 1u);
        uchar4 q;
        q.x = (unsigned char)cc.x; q.y = (unsigned char)cc.y;
        q.z = (unsigned char)cc.z; q.w = (unsigned char)cc.w;
        ((uchar4*)t8b)[i] = q;                   // one u32 store / 4 labels
    }
    for (int i = (n4 << 2) + threadIdx.x; i < count; i += 256) {
        int c = tb[i];
        atomicAdd(&hist[bucket_of(canon_key(xb[i]), c)], 1u);
        t8b[i] = (unsigned char)c;
    }
    __syncthreads();

    unsigned* og = counts + ((size_t)lb * nblk + blk) * NBKT;
    for (int i = threadIdx.x; i < NBKT; i += 256) og[i] = hist[i];
}

// K2 (fused transpose+scan): per 16-bucket group, exclusive-scan each bucket
// across chunks, write goff[seg][bkt] (without per-batch base) and totals.
// Requires nblk <= 512.
__global__ void __launch_bounds__(256)
rowscanT_kernel(const unsigned* __restrict__ counts,
                unsigned* __restrict__ goff,
                unsigned* __restrict__ totals, int nblk)
{
    __shared__ unsigned tile[512][SCAN_BKT];     // 32 KiB
    __shared__ unsigned part[16][SCAN_BKT];
    const int nbg  = NBKT / SCAN_BKT;            // 64
    const int lb   = blockIdx.x / nbg;
    const int bkt0 = (blockIdx.x % nbg) * SCAN_BKT;
    const int tx = threadIdx.x & 15;             // bucket lane
    const int ty = threadIdx.x >> 4;             // seg group 0..15

    const unsigned* cb = counts + (size_t)lb * nblk * NBKT;
    for (int seg = ty; seg < 512; seg += 16)
        tile[seg][tx] = (seg < nblk) ? cb[(size_t)seg * NBKT + bkt0 + tx] : 0u;
    __syncthreads();

    unsigned s = 0;
    #pragma unroll 8
    for (int j = 0; j < 32; ++j) s += tile[ty * 32 + j][tx];
    part[ty][tx] = s;
    __syncthreads();

    if (ty == 0) {                               // 16 threads: scan partials
        unsigned run = 0;
        #pragma unroll
        for (int j = 0; j < 16; ++j) {
            unsigned v = part[j][tx]; part[j][tx] = run; run += v;
        }
        totals[(size_t)lb * NBKT + bkt0 + tx] = run;
    }
    __syncthreads();

    unsigned run = part[ty][tx];
    unsigned* gb = goff + (size_t)lb * nblk * NBKT;
    for (int j = 0; j < 32; ++j) {
        int seg = ty * 32 + j;
        unsigned v = tile[seg][tx];
        if (seg < nblk) gb[(size_t)seg * NBKT + bkt0 + tx] = run;
        run += v;
    }
}

// K3: per-batch exclusive scan of 1024 bucket totals -> base[lb][0..1024]
// (sentinel base[1024] = N).
__global__ void __launch_bounds__(256)
basescan_kernel(const unsigned* __restrict__ totals, unsigned* __restrict__ base)
{
    __shared__ unsigned a[NBKT];
    const int lb = blockIdx.x, tid = threadIdx.x;
    const unsigned* tr = totals + (size_t)lb * NBKT;
    unsigned* br = base + (size_t)lb * (NBKT + 1);
    #pragma unroll
    for (int r = 0; r < 4; ++r) a[tid + r * 256] = tr[tid + r * 256];
    __syncthreads();
    for (int st = 1; st < NBKT; st <<= 1) {
        unsigned v[4];
        #pragma unroll
        for (int r = 0; r < 4; ++r) {
            int k = tid + r * 256;
            v[r] = a[k] + ((k >= st) ? a[k - st] : 0u);
        }
        __syncthreads();
        #pragma unroll
        for (int r = 0; r < 4; ++r) a[tid + r * 256] = v[r];
        __syncthreads();
    }
    #pragma unroll
    for (int r = 0; r < 4; ++r) {
        int k = tid + r * 256;
        br[k] = k ? a[k - 1] : 0u;
    }
    if (tid == 0) br[NBKT] = a[NBKT - 1];
}

// K4: placement scatter. Reads x + packed labels (t8). LDS counting sort of
// the chunk, then write each item to its exact globally-bucket-sorted
// position. Global run start = goff (chunk-exclusive) + base (bucket).
__global__ void __launch_bounds__(256)
scatter_kernel(const float* __restrict__ x, const unsigned char* __restrict__ t8,
               long long N, int bbase, int nblk,
               const unsigned* __restrict__ counts,
               const unsigned* __restrict__ goff,
               const unsigned* __restrict__ base,
               unsigned* __restrict__ keysout)
{
    __shared__ unsigned hist[NBKT];
    __shared__ unsigned sstart[NBKT];
    __shared__ unsigned lout[CHUNK];
    __shared__ unsigned short lbkt[CHUNK];
    __shared__ unsigned sscan[256];

    const int lb  = blockIdx.x / nblk;
    const int blk = blockIdx.x % nblk;
    const int b   = bbase + lb;
    const long long gbase = (long long)blk * CHUNK;
    const int count = (int)((N - gbase < CHUNK) ? (N - gbase) : CHUNK);
    const float* xb = x + (size_t)b * N + gbase;
    const unsigned char* t8b = t8 + (size_t)lb * N + gbase;
    const unsigned* crow = counts + ((size_t)lb * nblk + blk) * NBKT;
    const unsigned* grow = goff   + ((size_t)lb * nblk + blk) * NBKT;
    const unsigned* br   = base + (size_t)lb * (NBKT + 1);

    for (int i = threadIdx.x; i < NBKT; i += 256) hist[i] = crow[i];
    __syncthreads();

    unsigned h0 = hist[threadIdx.x * 4 + 0];
    unsigned h1 = hist[threadIdx.x * 4 + 1];
    unsigned h2 = hist[threadIdx.x * 4 + 2];
    unsigned h3 = hist[threadIdx.x * 4 + 3];
    unsigned local = h0 + h1 + h2 + h3;
    sscan[threadIdx.x] = local;
    __syncthreads();
    for (int st = 1; st < 256; st <<= 1) {
        unsigned v = (threadIdx.x >= (unsigned)st) ? sscan[threadIdx.x - st] : 0u;
        __syncthreads();
        sscan[threadIdx.x] += v;
        __syncthreads();
    }
    unsigned excl = sscan[threadIdx.x] - local;
    unsigned o0 = excl, o1 = o0 + h0, o2 = o1 + h1, o3 = o2 + h2;
    hist[threadIdx.x * 4 + 0] = o0; sstart[threadIdx.x * 4 + 0] = o0;
    hist[threadIdx.x * 4 + 1] = o1; sstart[threadIdx.x * 4 + 1] = o1;
    hist[threadIdx.x * 4 + 2] = o2; sstart[threadIdx.x * 4 + 2] = o2;
    hist[threadIdx.x * 4 + 3] = o3; sstart[threadIdx.x * 4 + 3] = o3;
    __syncthreads();

    const bool vec_ok = ((N & 3) == 0);
    const int n4 = vec_ok ? (count >> 2) : 0;
    for (int i = threadIdx.x; i < n4; i += 256) {
        float4 v  = ((const float4*)xb)[i];
        uchar4 cc = ((const uchar4*)t8b)[i];
        unsigned k, bk, p;
        k = canon_key(v.x); bk = bucket_of(k, cc.x);
        p = atomicAdd(&hist[bk], 1u); lout[p] = k; lbkt[p] = (unsigned short)bk;
        k = canon_key(v.y); bk = bucket_of(k, cc.y);
        p = atomicAdd(&hist[bk], 1u); lout[p] = k; lbkt[p] = (unsigned short)bk;
        k = canon_key(v.z); bk = bucket_of(k, cc.z);
        p = atomicAdd(&hist[bk], 1u); lout[p] = k; lbkt[p] = (unsigned short)bk;
        k = canon_key(v.w); bk = bucket_of(k, cc.w);
        p = atomicAdd(&hist[bk], 1u); lout[p] = k; lbkt[p] = (unsigned short)bk;
    }
    for (int i = (n4 << 2) + threadIdx.x; i < count; i += 256) {
        unsigned k = canon_key(xb[i]);
        unsigned bk = bucket_of(k, (int)t8b[i]);
        unsigned p = atomicAdd(&hist[bk], 1u);
        lout[p] = k; lbkt[p] = (unsigned short)bk;
    }
    __syncthreads();

    // delta = global run start - local run start
    for (int i = threadIdx.x; i < NBKT; i += 256)
        hist[i] = grow[i] + br[i] - sstart[i];
    __syncthreads();

    unsigned* kb = keysout + (size_t)lb * N;
    for (int i = threadIdx.x; i < count; i += 256)
        kb[hist[lbkt[i]] + i] = lout[i];
}

// K5: one block per (batch,bucket); bucket is one contiguous run.
// Batched initial CAS (4 overlapped) + per-item TIGHT cleanup loops --
// avoids re-issuing the full 4-slot masked body when one lane straggles
// (wave-convergence penalty identified in R8 post-mortem). Packed
// (count<<32 | key) LDS table; best = max(count<<32 | (2^32-1-ord(value))):
// max count, ties -> min value (reference tie-break).
__global__ void __launch_bounds__(512)
mode_kernel(const unsigned* __restrict__ keysout,
            const unsigned* __restrict__ base, long long N, int bbase,
            unsigned long long* __restrict__ best,   // [NUM_B*NUM_C], zeroed
            double* __restrict__ psum,               // [NUM_B*NBKT]
            unsigned* __restrict__ pcnt)             // [NUM_B*NBKT]
{
    __shared__ unsigned long long tab[TAB_SLOTS];    // 32 KiB
    __shared__ unsigned long long redb[8];
    __shared__ double reds[8];

    const unsigned lb  = blockIdx.x / NBKT;
    const unsigned bkt = blockIdx.x % NBKT;
    const unsigned c   = bkt >> 6;
    const unsigned b   = (unsigned)bbase + lb;
    const int tid = threadIdx.x;

    uint4* t4 = (uint4*)tab;                         // 2048 uint4
    const uint4 z4 = make_uint4(0u, 0u, 0u, 0u);
    for (int i = tid; i < TAB_SLOTS / 2; i += 512) t4[i] = z4;
    __syncthreads();

    const unsigned* br = base + (size_t)lb * (NBKT + 1);
    const unsigned s = br[bkt], e = br[bkt + 1];
    const unsigned* kb = keysout + (size_t)lb * N;

    double ls = 0.0;
    for (unsigned i0 = s + tid; i0 < e; i0 += 2048) {
        unsigned k[4], h[4];
        unsigned long long old[4];
        int nv = 0;                                  // valid slot count
        #pragma unroll
        for (int j = 0; j < 4; ++j) {
            unsigned idx = i0 + (unsigned)j * 512u;
            if (idx < e) {
                unsigned key = kb[idx];              // coalesced
                k[j] = key;
                h[j] = hash_u32(key) & (TAB_SLOTS - 1);
                ls += (double)__uint_as_float(key);
                nv = j + 1;
            }
        }
        #pragma unroll
        for (int j = 0; j < 4; ++j)                  // overlapped first CAS
            if (j < nv)
                old[j] = atomicCAS(&tab[h[j]], 0ull,
                                   (1ull << 32) | (unsigned long long)k[j]);
        #pragma unroll
        for (int j = 0; j < 4; ++j) {                // tight per-item cleanup
            if (j >= nv) continue;
            unsigned long long o = old[j];
            unsigned hh = h[j];
            const unsigned kk = k[j];
            while (o != 0ull) {
                if ((unsigned)o == kk) {
                    atomicAdd(&tab[hh], 1ull << 32);
                    break;
                }
                hh = (hh + 1u) & (TAB_SLOTS - 1);
                o = atomicCAS(&tab[hh], 0ull,
                              (1ull << 32) | (unsigned long long)kk);
            }
        }
    }
    __syncthreads();

    unsigned long long lbst = 0ull;
    for (int i = tid; i < TAB_SLOTS / 2; i += 512) {
        uint4 v = ((const uint4*)tab)[i];            // two slots per read
        if (v.y | v.x) {                             // slot0: key=x count=y
            unsigned ord = (v.x & 0x80000000u) ? ~v.x : (v.x | 0x80000000u);
            unsigned long long p = ((unsigned long long)v.y << 32)
                                 | (unsigned long long)(0xFFFFFFFFu - ord);
            if (p > lbst) lbst = p;
        }
        if (v.w | v.z) {                             // slot1: key=z count=w
            unsigned ord = (v.z & 0x80000000u) ? ~v.z : (v.z | 0x80000000u);
            unsigned long long p = ((unsigned long long)v.w << 32)
                                 | (unsigned long long)(0xFFFFFFFFu - ord);
            if (p > lbst) lbst = p;
        }
    }
    #pragma unroll
    for (int sh = 32; sh > 0; sh >>= 1) {
        unsigned long long ob = __shfl_down(lbst, sh);
        if (ob > lbst) lbst = ob;
        ls += __shfl_down(ls, sh);
    }
    const int wid = tid >> 6;
    if ((tid & 63) == 0) { redb[wid] = lbst; reds[wid] = ls; }
    __syncthreads();
    if (tid == 0) {
        unsigned long long bb = 0ull; double ss = 0.0;
        #pragma unroll
        for (int i = 0; i < 8; ++i) {
            if (redb[i] > bb) bb = redb[i];
            ss += reds[i];
        }
        psum[b * NBKT + bkt] = ss;
        pcnt[b * NBKT + bkt] = e - s;
        if (bb) atomicMax(&best[b * NUM_C + c], bb);
    }
}

// 128 threads, one per (b,c): fold 64 range-buckets, decode mode,
// out = sum_{b,c}(sum - cnt*mode) / (B*N).
__global__ void __launch_bounds__(128)
finalize_kernel(const double* __restrict__ psum,
                const unsigned* __restrict__ pcnt,
                const unsigned long long* __restrict__ best,
                float* __restrict__ out, double inv_total)
{
    __shared__ double acc[NUM_B * NUM_C];
    const int i = threadIdx.x;
    const int b = i >> 4, c = i & 15;

    double s = 0.0;
    unsigned long long cnt = 0ull;
    const double*   ps = psum + (size_t)b * NBKT + ((size_t)c << 6);
    const unsigned* pc = pcnt + (size_t)b * NBKT + ((size_t)c << 6);
    for (int r = 0; r < RANGES; ++r) { s += ps[r]; cnt += pc[r]; }

    double term = 0.0;
    if (cnt > 0ull) {
        unsigned long long p = best[i];
        unsigned ord = 0xFFFFFFFFu - (unsigned)(p & 0xFFFFFFFFull);
        unsigned ub  = (ord & 0x80000000u) ? (ord ^ 0x80000000u) : ~ord;
        float mode = __uint_as_float(ub);
        term = s - (double)cnt * (double)mode;
    }
    acc[i] = term;
    __syncthreads();
    for (int st = 64; st > 0; st >>= 1) {
        if (i < st) acc[i] += acc[i + st];
        __syncthreads();
    }
    if (i == 0) out[0] = (float)(acc[0] * inv_total);
}

extern "C" void kernel_launch(void* const* d_in, const int* in_sizes, int n_in,
                              void* d_out, int out_size, void* d_ws, size_t ws_size,
                              hipStream_t stream)
{
    const float* x = (const float*)d_in[0];
    const int*   t = (const int*)d_in[1];

    const long long total = in_sizes[0];
    const long long N = total / NUM_B;
    const int nblk = (int)((N + CHUNK - 1) / CHUNK);   // 489 for N=2M (<=512)

    char* ws = (char*)d_ws;
    size_t off = 0;
    unsigned long long* best = (unsigned long long*)(ws + off);
    off += (size_t)NUM_B * NUM_C * 8;
    double* psum = (double*)(ws + off);
    off += (size_t)NUM_B * NBKT * 8;
    unsigned* pcnt = (unsigned*)(ws + off);
    off += (size_t)NUM_B * NBKT * 4;
    unsigned* totals = (unsigned*)(ws + off);
    off += (size_t)MAX_NB * NBKT * 4;
    off = (off + 255) & ~(size_t)255;

    const size_t meta_per_b = (size_t)nblk * NBKT;     // counts / goff
    const size_t per_b = (size_t)N * 5 + 2 * meta_per_b * 4
                       + (NBKT + 1) * 4 + 512;         // keys + t8 + meta + base
    size_t remaining = ws_size - off;
    int nb = (int)(remaining / per_b);
    if (nb < 1) nb = 1;
    if (nb > MAX_NB) nb = MAX_NB;

    unsigned* keysout = (unsigned*)(ws + off);
    off += (size_t)nb * N * 4;
    unsigned* counts  = (unsigned*)(ws + off);
    off += (size_t)nb * meta_per_b * 4;
    unsigned* goff    = (unsigned*)(ws + off);
    off += (size_t)nb * meta_per_b * 4;
    unsigned* baseA   = (unsigned*)(ws + off);
    off += (size_t)nb * (NBKT + 1) * 4;
    off = (off + 255) & ~(size_t)255;
    unsigned char* t8 = (unsigned char*)(ws + off);

    hipMemsetAsync(best, 0, (size_t)NUM_B * NUM_C * 8, stream);
    for (int r = 0; r < NUM_B; r += nb) {
        const int nbr = (NUM_B - r < nb) ? (NUM_B - r) : nb;
        hist_kernel<<<nbr * nblk, 256, 0, stream>>>(
            x, t, N, r, nblk, counts, t8);
        rowscanT_kernel<<<nbr * (NBKT / SCAN_BKT), 256, 0, stream>>>(
            counts, goff, totals, nblk);
        basescan_kernel<<<nbr, 256, 0, stream>>>(totals, baseA);
        scatter_kernel<<<nbr * nblk, 256, 0, stream>>>(
            x, t8, N, r, nblk, counts, goff, baseA, keysout);
        mode_kernel<<<nbr * NBKT, 512, 0, stream>>>(
            keysout, baseA, N, r, best, psum, pcnt);
    }
    finalize_kernel<<<1, 128, 0, stream>>>(
        psum, pcnt, best, (float*)d_out,
        1.0 / ((double)NUM_B * (double)N));
}

// Round 10
// 340.223 us; speedup vs baseline: 1.2939x; 1.0199x over previous
//
#include <hip/hip_runtime.h>
#include <stdint.h>

#define NUM_C 16
#define NUM_B 8
#define RANGES 64                        // hash sub-ranges per class
#define NBKT (NUM_C * RANGES)            // 1024 buckets per batch
#define CHUNK 4096                       // items per scatter chunk
#define TAB_SLOTS 4096                   // LDS hash slots (load ~0.48)
#define MAX_NB 8                         // batches per round (ws-adaptive)
#define SCAN_BKT 16                      // buckets per rowscanT block

__device__ __forceinline__ unsigned hash_u32(unsigned h) {
    h ^= h >> 16; h *= 0x85ebca6bu;
    h ^= h >> 13; h *= 0xc2b2ae35u;
    h ^= h >> 16;
    return h;                            // invertible (xorshift-mul) mixer
}
__device__ __forceinline__ unsigned canon_key(float v) {
    unsigned k = __float_as_uint(v);
    return (k == 0x80000000u) ? 0u : k;  // -0.0 == +0.0
}
__device__ __forceinline__ unsigned bucket_of(unsigned key, int c) {
    return ((unsigned)c << 6) | (hash_u32(key) >> 26);
}
__device__ __forceinline__ unsigned long long pack_best(unsigned key,
                                                        unsigned cnt) {
    unsigned ord = (key & 0x80000000u) ? ~key : (key | 0x80000000u);
    return ((unsigned long long)cnt << 32)
         | (unsigned long long)(0xFFFFFFFFu - ord);
}

// K1: per-chunk bucket histogram -> counts[lb][seg][bkt]; also emits packed
// uchar labels (t8) so the scatter pass re-reads 1B/label instead of 4B.
__global__ void __launch_bounds__(256)
hist_kernel(const float* __restrict__ x, const int* __restrict__ t,
            long long N, int bbase, int nblk,
            unsigned* __restrict__ counts, unsigned char* __restrict__ t8)
{
    __shared__ unsigned hist[NBKT];
    const int lb  = blockIdx.x / nblk;
    const int blk = blockIdx.x % nblk;
    const int b   = bbase + lb;
    const long long base = (long long)blk * CHUNK;
    const int count = (int)((N - base < CHUNK) ? (N - base) : CHUNK);
    const float* xb = x + (size_t)b * N + base;
    const int*   tb = t + (size_t)b * N + base;
    unsigned char* t8b = t8 + (size_t)lb * N + base;

    for (int i = threadIdx.x; i < NBKT; i += 256) hist[i] = 0u;
    __syncthreads();

    const bool vec_ok = ((N & 3) == 0);
    const int n4 = vec_ok ? (count >> 2) : 0;
    for (int i = threadIdx.x; i < n4; i += 256) {
        float4 v  = ((const float4*)xb)[i];
        int4   cc = ((const int4*)tb)[i];
        atomicAdd(&hist[bucket_of(canon_key(v.x), cc.x)], 1u);
        atomicAdd(&hist[bucket_of(canon_key(v.y), cc.y)], 1u);
        atomicAdd(&hist[bucket_of(canon_key(v.z), cc.z)], 1u);
        atomicAdd(&hist[bucket_of(canon_key(v.w), cc.w)], 1u);
        uchar4 q;
        q.x = (unsigned char)cc.x; q.y = (unsigned char)cc.y;
        q.z = (unsigned char)cc.z; q.w = (unsigned char)cc.w;
        ((uchar4*)t8b)[i] = q;                   // one u32 store / 4 labels
    }
    for (int i = (n4 << 2) + threadIdx.x; i < count; i += 256) {
        int c = tb[i];
        atomicAdd(&hist[bucket_of(canon_key(xb[i]), c)], 1u);
        t8b[i] = (unsigned char)c;
    }
    __syncthreads();

    unsigned* og = counts + ((size_t)lb * nblk + blk) * NBKT;
    for (int i = threadIdx.x; i < NBKT; i += 256) og[i] = hist[i];
}

// K2 (fused transpose+scan): per 16-bucket group, exclusive-scan each bucket
// across chunks, write goff[seg][bkt] (without per-batch base) and totals.
// Requires nblk <= 512.
__global__ void __launch_bounds__(256)
rowscanT_kernel(const unsigned* __restrict__ counts,
                unsigned* __restrict__ goff,
                unsigned* __restrict__ totals, int nblk)
{
    __shared__ unsigned tile[512][SCAN_BKT];     // 32 KiB
    __shared__ unsigned part[16][SCAN_BKT];
    const int nbg  = NBKT / SCAN_BKT;            // 64
    const int lb   = blockIdx.x / nbg;
    const int bkt0 = (blockIdx.x % nbg) * SCAN_BKT;
    const int tx = threadIdx.x & 15;             // bucket lane
    const int ty = threadIdx.x >> 4;             // seg group 0..15

    const unsigned* cb = counts + (size_t)lb * nblk * NBKT;
    for (int seg = ty; seg < 512; seg += 16)
        tile[seg][tx] = (seg < nblk) ? cb[(size_t)seg * NBKT + bkt0 + tx] : 0u;
    __syncthreads();

    unsigned s = 0;
    #pragma unroll 8
    for (int j = 0; j < 32; ++j) s += tile[ty * 32 + j][tx];
    part[ty][tx] = s;
    __syncthreads();

    if (ty == 0) {                               // 16 threads: scan partials
        unsigned run = 0;
        #pragma unroll
        for (int j = 0; j < 16; ++j) {
            unsigned v = part[j][tx]; part[j][tx] = run; run += v;
        }
        totals[(size_t)lb * NBKT + bkt0 + tx] = run;
    }
    __syncthreads();

    unsigned run = part[ty][tx];
    unsigned* gb = goff + (size_t)lb * nblk * NBKT;
    for (int j = 0; j < 32; ++j) {
        int seg = ty * 32 + j;
        unsigned v = tile[seg][tx];
        if (seg < nblk) gb[(size_t)seg * NBKT + bkt0 + tx] = run;
        run += v;
    }
}

// K3: per-batch exclusive scan of 1024 bucket totals -> base[lb][0..1024]
// (sentinel base[1024] = N).
__global__ void __launch_bounds__(256)
basescan_kernel(const unsigned* __restrict__ totals, unsigned* __restrict__ base)
{
    __shared__ unsigned a[NBKT];
    const int lb = blockIdx.x, tid = threadIdx.x;
    const unsigned* tr = totals + (size_t)lb * NBKT;
    unsigned* br = base + (size_t)lb * (NBKT + 1);
    #pragma unroll
    for (int r = 0; r < 4; ++r) a[tid + r * 256] = tr[tid + r * 256];
    __syncthreads();
    for (int st = 1; st < NBKT; st <<= 1) {
        unsigned v[4];
        #pragma unroll
        for (int r = 0; r < 4; ++r) {
            int k = tid + r * 256;
            v[r] = a[k] + ((k >= st) ? a[k - st] : 0u);
        }
        __syncthreads();
        #pragma unroll
        for (int r = 0; r < 4; ++r) a[tid + r * 256] = v[r];
        __syncthreads();
    }
    #pragma unroll
    for (int r = 0; r < 4; ++r) {
        int k = tid + r * 256;
        br[k] = k ? a[k - 1] : 0u;
    }
    if (tid == 0) br[NBKT] = a[NBKT - 1];
}

// K4: placement scatter. Reads x + packed labels (t8). LDS counting sort of
// the chunk, then write each item to its exact globally-bucket-sorted
// position. Global run start = goff (chunk-exclusive) + base (bucket).
__global__ void __launch_bounds__(256)
scatter_kernel(const float* __restrict__ x, const unsigned char* __restrict__ t8,
               long long N, int bbase, int nblk,
               const unsigned* __restrict__ counts,
               const unsigned* __restrict__ goff,
               const unsigned* __restrict__ base,
               unsigned* __restrict__ keysout)
{
    __shared__ unsigned hist[NBKT];
    __shared__ unsigned sstart[NBKT];
    __shared__ unsigned lout[CHUNK];
    __shared__ unsigned short lbkt[CHUNK];
    __shared__ unsigned sscan[256];

    const int lb  = blockIdx.x / nblk;
    const int blk = blockIdx.x % nblk;
    const int b   = bbase + lb;
    const long long gbase = (long long)blk * CHUNK;
    const int count = (int)((N - gbase < CHUNK) ? (N - gbase) : CHUNK);
    const float* xb = x + (size_t)b * N + gbase;
    const unsigned char* t8b = t8 + (size_t)lb * N + gbase;
    const unsigned* crow = counts + ((size_t)lb * nblk + blk) * NBKT;
    const unsigned* grow = goff   + ((size_t)lb * nblk + blk) * NBKT;
    const unsigned* br   = base + (size_t)lb * (NBKT + 1);

    for (int i = threadIdx.x; i < NBKT; i += 256) hist[i] = crow[i];
    __syncthreads();

    unsigned h0 = hist[threadIdx.x * 4 + 0];
    unsigned h1 = hist[threadIdx.x * 4 + 1];
    unsigned h2 = hist[threadIdx.x * 4 + 2];
    unsigned h3 = hist[threadIdx.x * 4 + 3];
    unsigned local = h0 + h1 + h2 + h3;
    sscan[threadIdx.x] = local;
    __syncthreads();
    for (int st = 1; st < 256; st <<= 1) {
        unsigned v = (threadIdx.x >= (unsigned)st) ? sscan[threadIdx.x - st] : 0u;
        __syncthreads();
        sscan[threadIdx.x] += v;
        __syncthreads();
    }
    unsigned excl = sscan[threadIdx.x] - local;
    unsigned o0 = excl, o1 = o0 + h0, o2 = o1 + h1, o3 = o2 + h2;
    hist[threadIdx.x * 4 + 0] = o0; sstart[threadIdx.x * 4 + 0] = o0;
    hist[threadIdx.x * 4 + 1] = o1; sstart[threadIdx.x * 4 + 1] = o1;
    hist[threadIdx.x * 4 + 2] = o2; sstart[threadIdx.x * 4 + 2] = o2;
    hist[threadIdx.x * 4 + 3] = o3; sstart[threadIdx.x * 4 + 3] = o3;
    __syncthreads();

    const bool vec_ok = ((N & 3) == 0);
    const int n4 = vec_ok ? (count >> 2) : 0;
    for (int i = threadIdx.x; i < n4; i += 256) {
        float4 v  = ((const float4*)xb)[i];
        uchar4 cc = ((const uchar4*)t8b)[i];
        unsigned k, bk, p;
        k = canon_key(v.x); bk = bucket_of(k, cc.x);
        p = atomicAdd(&hist[bk], 1u); lout[p] = k; lbkt[p] = (unsigned short)bk;
        k = canon_key(v.y); bk = bucket_of(k, cc.y);
        p = atomicAdd(&hist[bk], 1u); lout[p] = k; lbkt[p] = (unsigned short)bk;
        k = canon_key(v.z); bk = bucket_of(k, cc.z);
        p = atomicAdd(&hist[bk], 1u); lout[p] = k; lbkt[p] = (unsigned short)bk;
        k = canon_key(v.w); bk = bucket_of(k, cc.w);
        p = atomicAdd(&hist[bk], 1u); lout[p] = k; lbkt[p] = (unsigned short)bk;
    }
    for (int i = (n4 << 2) + threadIdx.x; i < count; i += 256) {
        unsigned k = canon_key(xb[i]);
        unsigned bk = bucket_of(k, (int)t8b[i]);
        unsigned p = atomicAdd(&hist[bk], 1u);
        lout[p] = k; lbkt[p] = (unsigned short)bk;
    }
    __syncthreads();

    // delta = global run start - local run start
    for (int i = threadIdx.x; i < NBKT; i += 256)
        hist[i] = grow[i] + br[i] - sstart[i];
    __syncthreads();

    unsigned* kb = keysout + (size_t)lb * N;
    for (int i = threadIdx.x; i < count; i += 256)
        kb[hist[lbkt[i]] + i] = lout[i];
}

// K5: one block per (batch,bucket); bucket is one contiguous run.
// Incremental-max: best pack is tracked AT INSERT TIME from CAS/atomicAdd
// return values (fresh claim observes count=1, each increment observes
// count_old+1; the last incrementer of a key observes its final count, and
// smaller observations of the same key pack strictly lower) -- the final
// table scan is deleted entirely. Packed (count<<32 | key) LDS table;
// best = max(count<<32 | (2^32-1 - ord(value))): max count, ties -> min
// value (reference tie-break).
__global__ void __launch_bounds__(512)
mode_kernel(const unsigned* __restrict__ keysout,
            const unsigned* __restrict__ base, long long N, int bbase,
            unsigned long long* __restrict__ best,   // [NUM_B*NUM_C], zeroed
            double* __restrict__ psum,               // [NUM_B*NBKT]
            unsigned* __restrict__ pcnt)             // [NUM_B*NBKT]
{
    __shared__ unsigned long long tab[TAB_SLOTS];    // 32 KiB
    __shared__ unsigned long long redb[8];
    __shared__ double reds[8];

    const unsigned lb  = blockIdx.x / NBKT;
    const unsigned bkt = blockIdx.x % NBKT;
    const unsigned c   = bkt >> 6;
    const unsigned b   = (unsigned)bbase + lb;
    const int tid = threadIdx.x;

    uint4* t4 = (uint4*)tab;                         // 2048 uint4
    const uint4 z4 = make_uint4(0u, 0u, 0u, 0u);
    for (int i = tid; i < TAB_SLOTS / 2; i += 512) t4[i] = z4;
    __syncthreads();

    const unsigned* br = base + (size_t)lb * (NBKT + 1);
    const unsigned s = br[bkt], e = br[bkt + 1];
    const unsigned* kb = keysout + (size_t)lb * N;

    double ls = 0.0;
    unsigned long long lbst = 0ull;
    for (unsigned i0 = s + tid; i0 < e; i0 += 2048) {
        unsigned k[4], h[4];
        unsigned long long old[4];
        int nv = 0;                                  // valid slot count
        #pragma unroll
        for (int j = 0; j < 4; ++j) {
            unsigned idx = i0 + (unsigned)j * 512u;
            if (idx < e) {
                unsigned key = kb[idx];              // coalesced
                k[j] = key;
                h[j] = hash_u32(key) & (TAB_SLOTS - 1);
                ls += (double)__uint_as_float(key);
                nv = j + 1;
            }
        }
        #pragma unroll
        for (int j = 0; j < 4; ++j)                  // overlapped first CAS
            if (j < nv)
                old[j] = atomicCAS(&tab[h[j]], 0ull,
                                   (1ull << 32) | (unsigned long long)k[j]);
        #pragma unroll
        for (int j = 0; j < 4; ++j) {                // tight per-item cleanup
            if (j >= nv) continue;
            unsigned long long o = old[j];
            unsigned hh = h[j];
            const unsigned kk = k[j];
            unsigned cnt = 1u;                       // fresh-claim count
            while (o != 0ull) {
                if ((unsigned)o == kk) {             // duplicate: increment
                    unsigned long long prev =
                        atomicAdd(&tab[hh], 1ull << 32);
                    cnt = (unsigned)(prev >> 32) + 1u;
                    break;
                }
                hh = (hh + 1u) & (TAB_SLOTS - 1);
                o = atomicCAS(&tab[hh], 0ull,
                              (1ull << 32) | (unsigned long long)kk);
            }
            unsigned long long p = pack_best(kk, cnt);
            if (p > lbst) lbst = p;
        }
    }
    // no table scan: lbst already holds this thread's contribution

    #pragma unroll
    for (int sh = 32; sh > 0; sh >>= 1) {
        unsigned long long ob = __shfl_down(lbst, sh);
        if (ob > lbst) lbst = ob;
        ls += __shfl_down(ls, sh);
    }
    const int wid = tid >> 6;
    if ((tid & 63) == 0) { redb[wid] = lbst; reds[wid] = ls; }
    __syncthreads();
    if (tid == 0) {
        unsigned long long bb = 0ull; double ss = 0.0;
        #pragma unroll
        for (int i = 0; i < 8; ++i) {
            if (redb[i] > bb) bb = redb[i];
            ss += reds[i];
        }
        psum[b * NBKT + bkt] = ss;
        pcnt[b * NBKT + bkt] = e - s;
        if (bb) atomicMax(&best[b * NUM_C + c], bb);
    }
}

// 128 threads, one per (b,c): fold 64 range-buckets, decode mode,
// out = sum_{b,c}(sum - cnt*mode) / (B*N).
__global__ void __launch_bounds__(128)
finalize_kernel(const double* __restrict__ psum,
                const unsigned* __restrict__ pcnt,
                const unsigned long long* __restrict__ best,
                float* __restrict__ out, double inv_total)
{
    __shared__ double acc[NUM_B * NUM_C];
    const int i = threadIdx.x;
    const int b = i >> 4, c = i & 15;

    double s = 0.0;
    unsigned long long cnt = 0ull;
    const double*   ps = psum + (size_t)b * NBKT + ((size_t)c << 6);
    const unsigned* pc = pcnt + (size_t)b * NBKT + ((size_t)c << 6);
    for (int r = 0; r < RANGES; ++r) { s += ps[r]; cnt += pc[r]; }

    double term = 0.0;
    if (cnt > 0ull) {
        unsigned long long p = best[i];
        unsigned ord = 0xFFFFFFFFu - (unsigned)(p & 0xFFFFFFFFull);
        unsigned ub  = (ord & 0x80000000u) ? (ord ^ 0x80000000u) : ~ord;
        float mode = __uint_as_float(ub);
        term = s - (double)cnt * (double)mode;
    }
    acc[i] = term;
    __syncthreads();
    for (int st = 64; st > 0; st >>= 1) {
        if (i < st) acc[i] += acc[i + st];
        __syncthreads();
    }
    if (i == 0) out[0] = (float)(acc[0] * inv_total);
}

extern "C" void kernel_launch(void* const* d_in, const int* in_sizes, int n_in,
                              void* d_out, int out_size, void* d_ws, size_t ws_size,
                              hipStream_t stream)
{
    const float* x = (const float*)d_in[0];
    const int*   t = (const int*)d_in[1];

    const long long total = in_sizes[0];
    const long long N = total / NUM_B;
    const int nblk = (int)((N + CHUNK - 1) / CHUNK);   // 489 for N=2M (<=512)

    char* ws = (char*)d_ws;
    size_t off = 0;
    unsigned long long* best = (unsigned long long*)(ws + off);
    off += (size_t)NUM_B * NUM_C * 8;
    double* psum = (double*)(ws + off);
    off += (size_t)NUM_B * NBKT * 8;
    unsigned* pcnt = (unsigned*)(ws + off);
    off += (size_t)NUM_B * NBKT * 4;
    unsigned* totals = (unsigned*)(ws + off);
    off += (size_t)MAX_NB * NBKT * 4;
    off = (off + 255) & ~(size_t)255;

    const size_t meta_per_b = (size_t)nblk * NBKT;     // counts / goff
    const size_t per_b = (size_t)N * 5 + 2 * meta_per_b * 4
                       + (NBKT + 1) * 4 + 512;         // keys + t8 + meta + base
    size_t remaining = ws_size - off;
    int nb = (int)(remaining / per_b);
    if (nb < 1) nb = 1;
    if (nb > MAX_NB) nb = MAX_NB;

    unsigned* keysout = (unsigned*)(ws + off);
    off += (size_t)nb * N * 4;
    unsigned* counts  = (unsigned*)(ws + off);
    off += (size_t)nb * meta_per_b * 4;
    unsigned* goff    = (unsigned*)(ws + off);
    off += (size_t)nb * meta_per_b * 4;
    unsigned* baseA   = (unsigned*)(ws + off);
    off += (size_t)nb * (NBKT + 1) * 4;
    off = (off + 255) & ~(size_t)255;
    unsigned char* t8 = (unsigned char*)(ws + off);

    hipMemsetAsync(best, 0, (size_t)NUM_B * NUM_C * 8, stream);
    for (int r = 0; r < NUM_B; r += nb) {
        const int nbr = (NUM_B - r < nb) ? (NUM_B - r) : nb;
        hist_kernel<<<nbr * nblk, 256, 0, stream>>>(
            x, t, N, r, nblk, counts, t8);
        rowscanT_kernel<<<nbr * (NBKT / SCAN_BKT), 256, 0, stream>>>(
            counts, goff, totals, nblk);
        basescan_kernel<<<nbr, 256, 0, stream>>>(totals, baseA);
        scatter_kernel<<<nbr * nblk, 256, 0, stream>>>(
            x, t8, N, r, nblk, counts, goff, baseA, keysout);
        mode_kernel<<<nbr * NBKT, 512, 0, stream>>>(
            keysout, baseA, N, r, best, psum, pcnt);
    }
    finalize_kernel<<<1, 128, 0, stream>>>(
        psum, pcnt, best, (float*)d_out,
        1.0 / ((double)NUM_B * (double)N));
}

// Round 11
// 330.069 us; speedup vs baseline: 1.3337x; 1.0308x over previous
//
#include <hip/hip_runtime.h>
#include <stdint.h>

#define NUM_C 16
#define NUM_B 8
#define RANGES 64                        // hash sub-ranges per class
#define NBKT (NUM_C * RANGES)            // 1024 buckets per batch
#define NGRP 256                         // mode groups (4 buckets each)
#define CHUNK 4096                       // items per scatter chunk
#define TAB_SLOTS 4096                   // LDS hash slots (load ~0.48)
#define MAX_NB 8                         // batches per round (ws-adaptive)
#define SCAN_BKT 16                      // buckets per rowscanT block

__device__ __forceinline__ unsigned hash_u32(unsigned h) {
    h ^= h >> 16; h *= 0x85ebca6bu;
    h ^= h >> 13; h *= 0xc2b2ae35u;
    h ^= h >> 16;
    return h;                            // invertible (xorshift-mul) mixer
}
__device__ __forceinline__ unsigned canon_key(float v) {
    unsigned k = __float_as_uint(v);
    return (k == 0x80000000u) ? 0u : k;  // -0.0 == +0.0
}
__device__ __forceinline__ unsigned bucket_of(unsigned key, int c) {
    return ((unsigned)c << 6) | (hash_u32(key) >> 26);
}

// K1: per-chunk bucket histogram -> counts[lb][seg][bkt]; also emits packed
// uchar labels (t8) so the scatter pass re-reads 1B/label instead of 4B.
__global__ void __launch_bounds__(256)
hist_kernel(const float* __restrict__ x, const int* __restrict__ t,
            long long N, int bbase, int nblk,
            unsigned* __restrict__ counts, unsigned char* __restrict__ t8)
{
    __shared__ unsigned hist[NBKT];
    const int lb  = blockIdx.x / nblk;
    const int blk = blockIdx.x % nblk;
    const int b   = bbase + lb;
    const long long base = (long long)blk * CHUNK;
    const int count = (int)((N - base < CHUNK) ? (N - base) : CHUNK);
    const float* xb = x + (size_t)b * N + base;
    const int*   tb = t + (size_t)b * N + base;
    unsigned char* t8b = t8 + (size_t)lb * N + base;

    for (int i = threadIdx.x; i < NBKT; i += 256) hist[i] = 0u;
    __syncthreads();

    const bool vec_ok = ((N & 3) == 0);
    const int n4 = vec_ok ? (count >> 2) : 0;
    for (int i = threadIdx.x; i < n4; i += 256) {
        float4 v  = ((const float4*)xb)[i];
        int4   cc = ((const int4*)tb)[i];
        atomicAdd(&hist[bucket_of(canon_key(v.x), cc.x)], 1u);
        atomicAdd(&hist[bucket_of(canon_key(v.y), cc.y)], 1u);
        atomicAdd(&hist[bucket_of(canon_key(v.z), cc.z)], 1u);
        atomicAdd(&hist[bucket_of(canon_key(v.w), cc.w)], 1u);
        uchar4 q;
        q.x = (unsigned char)cc.x; q.y = (unsigned char)cc.y;
        q.z = (unsigned char)cc.z; q.w = (unsigned char)cc.w;
        ((uchar4*)t8b)[i] = q;                   // one u32 store / 4 labels
    }
    for (int i = (n4 << 2) + threadIdx.x; i < count; i += 256) {
        int c = tb[i];
        atomicAdd(&hist[bucket_of(canon_key(xb[i]), c)], 1u);
        t8b[i] = (unsigned char)c;
    }
    __syncthreads();

    unsigned* og = counts + ((size_t)lb * nblk + blk) * NBKT;
    for (int i = threadIdx.x; i < NBKT; i += 256) og[i] = hist[i];
}

// K2 (fused transpose+scan): per 16-bucket group, exclusive-scan each bucket
// across chunks, write goff[seg][bkt] (without per-batch base) and totals.
// Requires nblk <= 512.
__global__ void __launch_bounds__(256)
rowscanT_kernel(const unsigned* __restrict__ counts,
                unsigned* __restrict__ goff,
                unsigned* __restrict__ totals, int nblk)
{
    __shared__ unsigned tile[512][SCAN_BKT];     // 32 KiB
    __shared__ unsigned part[16][SCAN_BKT];
    const int nbg  = NBKT / SCAN_BKT;            // 64
    const int lb   = blockIdx.x / nbg;
    const int bkt0 = (blockIdx.x % nbg) * SCAN_BKT;
    const int tx = threadIdx.x & 15;             // bucket lane
    const int ty = threadIdx.x >> 4;             // seg group 0..15

    const unsigned* cb = counts + (size_t)lb * nblk * NBKT;
    for (int seg = ty; seg < 512; seg += 16)
        tile[seg][tx] = (seg < nblk) ? cb[(size_t)seg * NBKT + bkt0 + tx] : 0u;
    __syncthreads();

    unsigned s = 0;
    #pragma unroll 8
    for (int j = 0; j < 32; ++j) s += tile[ty * 32 + j][tx];
    part[ty][tx] = s;
    __syncthreads();

    if (ty == 0) {                               // 16 threads: scan partials
        unsigned run = 0;
        #pragma unroll
        for (int j = 0; j < 16; ++j) {
            unsigned v = part[j][tx]; part[j][tx] = run; run += v;
        }
        totals[(size_t)lb * NBKT + bkt0 + tx] = run;
    }
    __syncthreads();

    unsigned run = part[ty][tx];
    unsigned* gb = goff + (size_t)lb * nblk * NBKT;
    for (int j = 0; j < 32; ++j) {
        int seg = ty * 32 + j;
        unsigned v = tile[seg][tx];
        if (seg < nblk) gb[(size_t)seg * NBKT + bkt0 + tx] = run;
        run += v;
    }
}

// K3: per-batch exclusive scan of 1024 bucket totals -> base[lb][0..1024]
// (sentinel base[1024] = N).
__global__ void __launch_bounds__(256)
basescan_kernel(const unsigned* __restrict__ totals, unsigned* __restrict__ base)
{
    __shared__ unsigned a[NBKT];
    const int lb = blockIdx.x, tid = threadIdx.x;
    const unsigned* tr = totals + (size_t)lb * NBKT;
    unsigned* br = base + (size_t)lb * (NBKT + 1);
    #pragma unroll
    for (int r = 0; r < 4; ++r) a[tid + r * 256] = tr[tid + r * 256];
    __syncthreads();
    for (int st = 1; st < NBKT; st <<= 1) {
        unsigned v[4];
        #pragma unroll
        for (int r = 0; r < 4; ++r) {
            int k = tid + r * 256;
            v[r] = a[k] + ((k >= st) ? a[k - st] : 0u);
        }
        __syncthreads();
        #pragma unroll
        for (int r = 0; r < 4; ++r) a[tid + r * 256] = v[r];
        __syncthreads();
    }
    #pragma unroll
    for (int r = 0; r < 4; ++r) {
        int k = tid + r * 256;
        br[k] = k ? a[k - 1] : 0u;
    }
    if (tid == 0) br[NBKT] = a[NBKT - 1];
}

// K4: placement scatter. Reads x + packed labels (t8). LDS counting sort of
// the chunk, then write each item to its exact globally-bucket-sorted
// position. Global run start = goff (chunk-exclusive) + base (bucket).
__global__ void __launch_bounds__(256)
scatter_kernel(const float* __restrict__ x, const unsigned char* __restrict__ t8,
               long long N, int bbase, int nblk,
               const unsigned* __restrict__ counts,
               const unsigned* __restrict__ goff,
               const unsigned* __restrict__ base,
               unsigned* __restrict__ keysout)
{
    __shared__ unsigned hist[NBKT];
    __shared__ unsigned sstart[NBKT];
    __shared__ unsigned lout[CHUNK];
    __shared__ unsigned short lbkt[CHUNK];
    __shared__ unsigned sscan[256];

    const int lb  = blockIdx.x / nblk;
    const int blk = blockIdx.x % nblk;
    const int b   = bbase + lb;
    const long long gbase = (long long)blk * CHUNK;
    const int count = (int)((N - gbase < CHUNK) ? (N - gbase) : CHUNK);
    const float* xb = x + (size_t)b * N + gbase;
    const unsigned char* t8b = t8 + (size_t)lb * N + gbase;
    const unsigned* crow = counts + ((size_t)lb * nblk + blk) * NBKT;
    const unsigned* grow = goff   + ((size_t)lb * nblk + blk) * NBKT;
    const unsigned* br   = base + (size_t)lb * (NBKT + 1);

    for (int i = threadIdx.x; i < NBKT; i += 256) hist[i] = crow[i];
    __syncthreads();

    unsigned h0 = hist[threadIdx.x * 4 + 0];
    unsigned h1 = hist[threadIdx.x * 4 + 1];
    unsigned h2 = hist[threadIdx.x * 4 + 2];
    unsigned h3 = hist[threadIdx.x * 4 + 3];
    unsigned local = h0 + h1 + h2 + h3;
    sscan[threadIdx.x] = local;
    __syncthreads();
    for (int st = 1; st < 256; st <<= 1) {
        unsigned v = (threadIdx.x >= (unsigned)st) ? sscan[threadIdx.x - st] : 0u;
        __syncthreads();
        sscan[threadIdx.x] += v;
        __syncthreads();
    }
    unsigned excl = sscan[threadIdx.x] - local;
    unsigned o0 = excl, o1 = o0 + h0, o2 = o1 + h1, o3 = o2 + h2;
    hist[threadIdx.x * 4 + 0] = o0; sstart[threadIdx.x * 4 + 0] = o0;
    hist[threadIdx.x * 4 + 1] = o1; sstart[threadIdx.x * 4 + 1] = o1;
    hist[threadIdx.x * 4 + 2] = o2; sstart[threadIdx.x * 4 + 2] = o2;
    hist[threadIdx.x * 4 + 3] = o3; sstart[threadIdx.x * 4 + 3] = o3;
    __syncthreads();

    const bool vec_ok = ((N & 3) == 0);
    const int n4 = vec_ok ? (count >> 2) : 0;
    for (int i = threadIdx.x; i < n4; i += 256) {
        float4 v  = ((const float4*)xb)[i];
        uchar4 cc = ((const uchar4*)t8b)[i];
        unsigned k, bk, p;
        k = canon_key(v.x); bk = bucket_of(k, cc.x);
        p = atomicAdd(&hist[bk], 1u); lout[p] = k; lbkt[p] = (unsigned short)bk;
        k = canon_key(v.y); bk = bucket_of(k, cc.y);
        p = atomicAdd(&hist[bk], 1u); lout[p] = k; lbkt[p] = (unsigned short)bk;
        k = canon_key(v.z); bk = bucket_of(k, cc.z);
        p = atomicAdd(&hist[bk], 1u); lout[p] = k; lbkt[p] = (unsigned short)bk;
        k = canon_key(v.w); bk = bucket_of(k, cc.w);
        p = atomicAdd(&hist[bk], 1u); lout[p] = k; lbkt[p] = (unsigned short)bk;
    }
    for (int i = (n4 << 2) + threadIdx.x; i < count; i += 256) {
        unsigned k = canon_key(xb[i]);
        unsigned bk = bucket_of(k, (int)t8b[i]);
        unsigned p = atomicAdd(&hist[bk], 1u);
        lout[p] = k; lbkt[p] = (unsigned short)bk;
    }
    __syncthreads();

    // delta = global run start - local run start
    for (int i = threadIdx.x; i < NBKT; i += 256)
        hist[i] = grow[i] + br[i] - sstart[i];
    __syncthreads();

    unsigned* kb = keysout + (size_t)lb * N;
    for (int i = threadIdx.x; i < count; i += 256)
        kb[hist[lbkt[i]] + i] = lout[i];
}

// K5: one block per (batch, 4-bucket group); each bucket is a contiguous
// run. 32-BIT split tables: keyt stores ord(key) (0 = empty; only -NaN maps
// to 0, inputs are finite), cntm1 stores count-1. Singleton items (~98%)
// cost exactly ONE 32-bit LDS CAS and zero 64-bit VALU ops; duplicates add
// one 32-bit atomicAdd whose return value gives the observed count (prev+2).
// Incremental best tracked as 32-bit (cnt, ord) pair; packed to
// (cnt<<32 | ~ord) only in the single per-group epilogue. Max count, ties
// -> smallest value (reference tie-break; ord is order-preserving).
__global__ void __launch_bounds__(512)
mode_kernel(const unsigned* __restrict__ keysout,
            const unsigned* __restrict__ base, long long N, int bbase,
            unsigned long long* __restrict__ best,   // [NUM_B*NUM_C], zeroed
            double* __restrict__ psum,               // [NUM_B*NGRP]
            unsigned* __restrict__ pcnt)             // [NUM_B*NGRP]
{
    __shared__ unsigned keyt[TAB_SLOTS];             // 16 KiB, ord or 0
    __shared__ unsigned cntm1[TAB_SLOTS];            // 16 KiB, count-1
    __shared__ unsigned long long redb[8];
    __shared__ double reds[8];

    const unsigned lb = blockIdx.x / NGRP;
    const unsigned g  = blockIdx.x % NGRP;
    const unsigned c  = g >> 4;                      // 16 groups per class
    const unsigned b  = (unsigned)bbase + lb;
    const int tid = threadIdx.x;

    const uint4 z4 = make_uint4(0u, 0u, 0u, 0u);
    for (int i = tid; i < TAB_SLOTS / 4; i += 512) {
        ((uint4*)keyt)[i]  = z4;
        ((uint4*)cntm1)[i] = z4;
    }
    __syncthreads();

    const unsigned* br = base + (size_t)lb * (NBKT + 1) + g * 4;
    const unsigned* kb = keysout + (size_t)lb * N;

    double ls = 0.0;
    unsigned bc = 0u, bo = 0xFFFFFFFFu;              // best (count, ord)

    for (int sb = 0; sb < 4; ++sb) {
        const unsigned s = br[sb], e = br[sb + 1];
        for (unsigned i0 = s + tid; i0 < e; i0 += 2048) {
            unsigned od[4], h[4], old[4];
            int nv = 0;
            #pragma unroll
            for (int j = 0; j < 4; ++j) {
                unsigned idx = i0 + (unsigned)j * 512u;
                if (idx < e) {
                    unsigned key = kb[idx];          // coalesced
                    unsigned o = (key & 0x80000000u) ? ~key
                                                     : (key | 0x80000000u);
                    od[j] = o;
                    h[j] = hash_u32(o) & (TAB_SLOTS - 1);
                    ls += (double)__uint_as_float(key);
                    nv = j + 1;
                }
            }
            #pragma unroll
            for (int j = 0; j < 4; ++j)              // overlapped first CAS
                if (j < nv) old[j] = atomicCAS(&keyt[h[j]], 0u, od[j]);
            #pragma unroll
            for (int j = 0; j < 4; ++j) {            // tight per-item cleanup
                if (j >= nv) continue;
                unsigned o = old[j];
                unsigned hh = h[j];
                const unsigned oo = od[j];
                unsigned cnt = 1u;                   // fresh-claim count
                while (o != 0u) {
                    if (o == oo) {                   // duplicate: bump count
                        cnt = atomicAdd(&cntm1[hh], 1u) + 2u;
                        break;
                    }
                    hh = (hh + 1u) & (TAB_SLOTS - 1);
                    o = atomicCAS(&keyt[hh], 0u, oo);
                }
                if (cnt > bc || (cnt == bc && oo < bo)) { bc = cnt; bo = oo; }
            }
        }
        if (sb < 3) {                                // re-clear for next bucket
            __syncthreads();
            for (int i = tid; i < TAB_SLOTS / 4; i += 512) {
                ((uint4*)keyt)[i]  = z4;
                ((uint4*)cntm1)[i] = z4;
            }
            __syncthreads();
        }
    }

    // single epilogue for the 4-bucket group
    unsigned long long lbst = ((unsigned long long)bc << 32)
                            | (unsigned long long)(~bo);   // 0 if bc==0
    #pragma unroll
    for (int sh = 32; sh > 0; sh >>= 1) {
        unsigned long long ob = __shfl_down(lbst, sh);
        if (ob > lbst) lbst = ob;
        ls += __shfl_down(ls, sh);
    }
    const int wid = tid >> 6;
    if ((tid & 63) == 0) { redb[wid] = lbst; reds[wid] = ls; }
    __syncthreads();
    if (tid == 0) {
        unsigned long long bb = 0ull; double ss = 0.0;
        #pragma unroll
        for (int i = 0; i < 8; ++i) {
            if (redb[i] > bb) bb = redb[i];
            ss += reds[i];
        }
        psum[b * NGRP + g] = ss;
        pcnt[b * NGRP + g] = br[4] - br[0];
        if (bb) atomicMax(&best[b * NUM_C + c], bb);
    }
}

// 128 threads, one per (b,c): fold 16 groups, decode mode,
// out = sum_{b,c}(sum - cnt*mode) / (B*N).
__global__ void __launch_bounds__(128)
finalize_kernel(const double* __restrict__ psum,
                const unsigned* __restrict__ pcnt,
                const unsigned long long* __restrict__ best,
                float* __restrict__ out, double inv_total)
{
    __shared__ double acc[NUM_B * NUM_C];
    const int i = threadIdx.x;
    const int b = i >> 4, c = i & 15;

    double s = 0.0;
    unsigned long long cnt = 0ull;
    const double*   ps = psum + (size_t)b * NGRP + ((size_t)c << 4);
    const unsigned* pc = pcnt + (size_t)b * NGRP + ((size_t)c << 4);
    for (int r = 0; r < 16; ++r) { s += ps[r]; cnt += pc[r]; }

    double term = 0.0;
    if (cnt > 0ull) {
        unsigned long long p = best[i];
        unsigned ord = 0xFFFFFFFFu - (unsigned)(p & 0xFFFFFFFFull);
        unsigned ub  = (ord & 0x80000000u) ? (ord ^ 0x80000000u) : ~ord;
        float mode = __uint_as_float(ub);
        term = s - (double)cnt * (double)mode;
    }
    acc[i] = term;
    __syncthreads();
    for (int st = 64; st > 0; st >>= 1) {
        if (i < st) acc[i] += acc[i + st];
        __syncthreads();
    }
    if (i == 0) out[0] = (float)(acc[0] * inv_total);
}

extern "C" void kernel_launch(void* const* d_in, const int* in_sizes, int n_in,
                              void* d_out, int out_size, void* d_ws, size_t ws_size,
                              hipStream_t stream)
{
    const float* x = (const float*)d_in[0];
    const int*   t = (const int*)d_in[1];

    const long long total = in_sizes[0];
    const long long N = total / NUM_B;
    const int nblk = (int)((N + CHUNK - 1) / CHUNK);   // 489 for N=2M (<=512)

    char* ws = (char*)d_ws;
    size_t off = 0;
    unsigned long long* best = (unsigned long long*)(ws + off);
    off += (size_t)NUM_B * NUM_C * 8;
    double* psum = (double*)(ws + off);
    off += (size_t)NUM_B * NGRP * 8;
    unsigned* pcnt = (unsigned*)(ws + off);
    off += (size_t)NUM_B * NGRP * 4;
    unsigned* totals = (unsigned*)(ws + off);
    off += (size_t)MAX_NB * NBKT * 4;
    off = (off + 255) & ~(size_t)255;

    const size_t meta_per_b = (size_t)nblk * NBKT;     // counts / goff
    const size_t per_b = (size_t)N * 5 + 2 * meta_per_b * 4
                       + (NBKT + 1) * 4 + 512;         // keys + t8 + meta + base
    size_t remaining = ws_size - off;
    int nb = (int)(remaining / per_b);
    if (nb < 1) nb = 1;
    if (nb > MAX_NB) nb = MAX_NB;

    unsigned* keysout = (unsigned*)(ws + off);
    off += (size_t)nb * N * 4;
    unsigned* counts  = (unsigned*)(ws + off);
    off += (size_t)nb * meta_per_b * 4;
    unsigned* goff    = (unsigned*)(ws + off);
    off += (size_t)nb * meta_per_b * 4;
    unsigned* baseA   = (unsigned*)(ws + off);
    off += (size_t)nb * (NBKT + 1) * 4;
    off = (off + 255) & ~(size_t)255;
    unsigned char* t8 = (unsigned char*)(ws + off);

    hipMemsetAsync(best, 0, (size_t)NUM_B * NUM_C * 8, stream);
    for (int r = 0; r < NUM_B; r += nb) {
        const int nbr = (NUM_B - r < nb) ? (NUM_B - r) : nb;
        hist_kernel<<<nbr * nblk, 256, 0, stream>>>(
            x, t, N, r, nblk, counts, t8);
        rowscanT_kernel<<<nbr * (NBKT / SCAN_BKT), 256, 0, stream>>>(
            counts, goff, totals, nblk);
        basescan_kernel<<<nbr, 256, 0, stream>>>(totals, baseA);
        scatter_kernel<<<nbr * nblk, 256, 0, stream>>>(
            x, t8, N, r, nblk, counts, goff, baseA, keysout);
        mode_kernel<<<nbr * NGRP, 512, 0, stream>>>(
            keysout, baseA, N, r, best, psum, pcnt);
    }
    finalize_kernel<<<1, 128, 0, stream>>>(
        psum, pcnt, best, (float*)d_out,
        1.0 / ((double)NUM_B * (double)N));
}